// Round 1
// baseline (6419.437 us; speedup 1.0000x reference)
//
#include <hip/hip_runtime.h>
#include <hip/hip_bf16.h>
#include <stdint.h>

#define V_ 32000
#define D_ 512
#define H_ 8
#define L_ 6
#define S_ 1024
#define B_ 4
#define DH_ 64
#define M_ (B_*S_)   // 4096

typedef __attribute__((ext_vector_type(8))) short bf16x8;
typedef __attribute__((ext_vector_type(4))) float f32x4;

__device__ __forceinline__ short f2bs(float f) {
  union { float f; uint32_t u; } x; x.f = f;
  uint32_t r = (x.u + 0x7FFFu + ((x.u >> 16) & 1u)) >> 16;
  return (short)r;
}
__device__ __forceinline__ float bs2f(short s) {
  union { uint32_t u; float f; } x; x.u = ((uint32_t)(uint16_t)s) << 16;
  return x.f;
}

__device__ __forceinline__ f32x4 mfma16(bf16x8 a, bf16x8 b, f32x4 c) {
  return __builtin_amdgcn_mfma_f32_16x16x32_bf16(a, b, c, 0, 0, 0);
}

// ---- transpose + fp32->bf16 convert: out[n*K+k] = in[k*N+n], per blockIdx.z slab ----
__global__ __launch_bounds__(256) void transpose_cvt(const float* __restrict__ in,
    short* __restrict__ out, int K, int N) {
  __shared__ float tile[32][33];
  const float* inp = in + (size_t)blockIdx.z * K * N;
  short* outp = out + (size_t)blockIdx.z * K * N;
  int kb = blockIdx.y * 32, nb = blockIdx.x * 32;
  int tx = threadIdx.x, ty = threadIdx.y;   // block (32,8)
  for (int r = ty; r < 32; r += 8) {
    int k = kb + r, n = nb + tx;
    tile[r][tx] = (k < K && n < N) ? inp[(size_t)k * N + n] : 0.f;
  }
  __syncthreads();
  for (int r = ty; r < 32; r += 8) {
    int n = nb + r, k = kb + tx;
    if (n < N && k < K) outp[(size_t)n * K + k] = f2bs(tile[tx][r]);
  }
}

// ---- embedding: h[bs,:] = tok_emb[ids[bs],:] + pos_emb[bs%S,:] ----
__global__ __launch_bounds__(256) void embed_k(const int* __restrict__ ids,
    const float* __restrict__ tok, const float* __restrict__ pos, float* __restrict__ h) {
  int bs = blockIdx.x;
  int tid = threadIdx.x;
  int s = bs & (S_ - 1);
  int id = ids[bs];
  float2 te = *(const float2*)(tok + (size_t)id * D_ + tid * 2);
  float2 pe = *(const float2*)(pos + (size_t)s * D_ + tid * 2);
  float2 r; r.x = te.x + pe.x; r.y = te.y + pe.y;
  *(float2*)(h + (size_t)bs * D_ + tid * 2) = r;
}

// ---- LayerNorm (one row of 512 per block) -> bf16 out ----
__global__ __launch_bounds__(256) void ln_k(const float* __restrict__ in,
    const float* __restrict__ w, const float* __restrict__ bb, short* __restrict__ outb) {
  int row = blockIdx.x, tid = threadIdx.x;
  int lane = tid & 63, wv = tid >> 6;
  const float* x = in + (size_t)row * D_;
  float2 v = *(const float2*)(x + tid * 2);
  float s = v.x + v.y;
  #pragma unroll
  for (int o = 32; o; o >>= 1) s += __shfl_xor(s, o);
  __shared__ float red[8];
  if (lane == 0) red[wv] = s;
  __syncthreads();
  float mu = (red[0] + red[1] + red[2] + red[3]) * (1.f / D_);
  float dx = v.x - mu, dy = v.y - mu;
  float s2 = dx * dx + dy * dy;
  #pragma unroll
  for (int o = 32; o; o >>= 1) s2 += __shfl_xor(s2, o);
  if (lane == 0) red[4 + wv] = s2;
  __syncthreads();
  float var = (red[4] + red[5] + red[6] + red[7]) * (1.f / D_);
  float rs = rsqrtf(var + 1e-5f);
  int c = tid * 2;
  float y0 = dx * rs * w[c] + bb[c];
  float y1 = dy * rs * w[c + 1] + bb[c + 1];
  short* o2 = outb + (size_t)row * D_ + c;
  o2[0] = f2bs(y0); o2[1] = f2bs(y1);
}

// ---- generic bf16 MFMA GEMM, 64x64 tile, 4 waves of 32x32 ----
// AMODE: 0 plain A[m*K+k]; 1 concat(t[m],t[m+1]) (K=1024, zero 2nd half at batch end);
//        2 shifted msg (A[m]=msg[m-1], zero at batch start)
// EMODE: 0 Cf=acc+bias (+optional bf16 Cb); 1 Cf+=acc+bias (residual);
//        2 Cb=bf16(relu(acc+bias)); 3 gate: t+=sigmoid(acc+bias)*agg, write Cf,Cb
template<int AMODE, int EMODE>
__global__ __launch_bounds__(256) void gemm_k(
    const short* __restrict__ A, const short* __restrict__ Wt,
    const float* __restrict__ bias, float* __restrict__ Cf,
    short* __restrict__ Cb, const short* __restrict__ Agg,
    int M, int N, int K)
{
  __shared__ short As[64][40];
  __shared__ short Bs[64][40];
  int tid = threadIdx.x;
  int m0 = blockIdx.y * 64, n0 = blockIdx.x * 64;
  int lane = tid & 63, w = tid >> 6;
  int wm = (w >> 1) * 32, wn = (w & 1) * 32;
  int l15 = lane & 15, l4 = lane >> 4;
  f32x4 acc[2][2] = {};
  int ar = tid >> 2, ac = (tid & 3) * 8;
  int gm = m0 + ar;
  const uint4 zz = make_uint4(0u, 0u, 0u, 0u);
  for (int k0 = 0; k0 < K; k0 += 32) {
    int gk = k0 + ac;
    uint4 av, bvv;
    if (AMODE == 0) {
      av = *(const uint4*)(A + (size_t)gm * K + gk);
    } else if (AMODE == 1) {
      if (gk < D_) av = *(const uint4*)(A + (size_t)gm * D_ + gk);
      else if ((gm & (S_ - 1)) == S_ - 1) av = zz;
      else av = *(const uint4*)(A + (size_t)(gm + 1) * D_ + (gk - D_));
    } else {
      if ((gm & (S_ - 1)) == 0) av = zz;
      else av = *(const uint4*)(A + (size_t)(gm - 1) * D_ + gk);
    }
    bvv = *(const uint4*)(Wt + (size_t)(n0 + ar) * K + gk);
    __syncthreads();
    *(uint4*)&As[ar][ac] = av;
    *(uint4*)&Bs[ar][ac] = bvv;
    __syncthreads();
    bf16x8 a0 = *(const bf16x8*)&As[wm + l15][l4 * 8];
    bf16x8 a1 = *(const bf16x8*)&As[wm + 16 + l15][l4 * 8];
    bf16x8 b0 = *(const bf16x8*)&Bs[wn + l15][l4 * 8];
    bf16x8 b1 = *(const bf16x8*)&Bs[wn + 16 + l15][l4 * 8];
    acc[0][0] = mfma16(a0, b0, acc[0][0]);
    acc[0][1] = mfma16(a0, b1, acc[0][1]);
    acc[1][0] = mfma16(a1, b0, acc[1][0]);
    acc[1][1] = mfma16(a1, b1, acc[1][1]);
  }
  int rowb = m0 + wm + l4 * 4;
  int colb = n0 + wn + l15;
  #pragma unroll
  for (int fm = 0; fm < 2; ++fm) {
    #pragma unroll
    for (int fn = 0; fn < 2; ++fn) {
      int col = colb + fn * 16;
      float bias_v = bias ? bias[col] : 0.f;
      #pragma unroll
      for (int r = 0; r < 4; ++r) {
        int row = rowb + fm * 16 + r;
        size_t idx = (size_t)row * N + col;
        float v = acc[fm][fn][r] + bias_v;
        if (EMODE == 0) {
          Cf[idx] = v;
          if (Cb) Cb[idx] = f2bs(v);
        } else if (EMODE == 1) {
          Cf[idx] += v;
        } else if (EMODE == 2) {
          v = fmaxf(v, 0.f);
          Cb[idx] = f2bs(v);
        } else {
          float g = 1.f / (1.f + __expf(-v));
          float aggv = ((row & (S_ - 1)) == 0) ? 0.f : bs2f(Agg[(size_t)(row - 1) * N + col]);
          float tn = Cf[idx] + g * aggv;
          Cf[idx] = tn;
          Cb[idx] = f2bs(tn);
        }
      }
    }
  }
}

// ---- attention: one wave per query row, online softmax, shfl-broadcast PV ----
__global__ __launch_bounds__(256) void attn_k(const float* __restrict__ Q,
    const float* __restrict__ Kk, const float* __restrict__ Vv, short* __restrict__ avb)
{
  __shared__ float qs[4][DH_];
  int tid = threadIdx.x, lane = tid & 63, w = tid >> 6;
  int row = blockIdx.x * 4 + w;
  int qi = row & (S_ - 1);
  int bh = row >> 10;                 // S_=1024
  int b = bh >> 3, hh = bh & 7;       // H_=8
  const float* qp = Q + ((size_t)(b * S_ + qi) * H_ + hh) * DH_;
  qs[w][lane] = qp[lane] * 0.125f;    // 1/sqrt(64)
  __syncthreads();
  const float* kbase = Kk + ((size_t)b * S_ * H_ + hh) * DH_;
  const float* vbase0 = Vv + ((size_t)b * S_ * H_ + hh) * DH_ + lane;
  float m = -1e30f, lsum = 0.f, acc = 0.f;
  for (int base = 0; base <= qi; base += 64) {
    int j = base + lane;
    float s = -1e30f;
    if (j <= qi) {
      const float4* kp = (const float4*)(kbase + (size_t)j * (H_ * DH_));
      float d0 = 0.f;
      #pragma unroll
      for (int d4 = 0; d4 < DH_ / 4; ++d4) {
        float4 kv = kp[d4];
        d0 += qs[w][d4*4+0]*kv.x + qs[w][d4*4+1]*kv.y + qs[w][d4*4+2]*kv.z + qs[w][d4*4+3]*kv.w;
      }
      s = d0;
    }
    float cm = s;
    #pragma unroll
    for (int o = 32; o; o >>= 1) cm = fmaxf(cm, __shfl_xor(cm, o));
    float mn = fmaxf(m, cm);
    float f = __expf(m - mn);
    float e = (j <= qi) ? __expf(s - mn) : 0.f;
    float cs = e;
    #pragma unroll
    for (int o = 32; o; o >>= 1) cs += __shfl_xor(cs, o);
    lsum = lsum * f + cs;
    acc *= f;
    const float* vp = vbase0 + (size_t)base * (H_ * DH_);
    int cnt = qi - base + 1; if (cnt > 64) cnt = 64;
    for (int src = 0; src < cnt; ++src) {
      float pj = __shfl(e, src);
      acc += pj * vp[(size_t)src * (H_ * DH_)];
    }
    m = mn;
  }
  acc /= lsum;
  avb[(size_t)(b * S_ + qi) * D_ + hh * DH_ + lane] = f2bs(acc);
}

// ---- h += t ----
__global__ __launch_bounds__(256) void add_k(float* __restrict__ h,
    const float* __restrict__ t, int n4) {
  int i = blockIdx.x * 256 + threadIdx.x;
  if (i < n4) {
    float4 a = ((const float4*)h)[i];
    float4 c = ((const float4*)t)[i];
    a.x += c.x; a.y += c.y; a.z += c.z; a.w += c.w;
    ((float4*)h)[i] = a;
  }
}

extern "C" void kernel_launch(void* const* d_in, const int* in_sizes, int n_in,
                              void* d_out, int out_size, void* d_ws, size_t ws_size,
                              hipStream_t stream) {
  const int*   ids   = (const int*)d_in[0];
  const float* tok   = (const float*)d_in[1];
  const float* pos   = (const float*)d_in[2];
  const float* Wq    = (const float*)d_in[3];
  const float* bq    = (const float*)d_in[4];
  const float* Wk    = (const float*)d_in[5];
  const float* bk    = (const float*)d_in[6];
  const float* Wv    = (const float*)d_in[7];
  const float* bv    = (const float*)d_in[8];
  const float* Wo    = (const float*)d_in[9];
  const float* bo    = (const float*)d_in[10];
  const float* ln1w  = (const float*)d_in[11];
  const float* ln1b  = (const float*)d_in[12];
  const float* ln2w  = (const float*)d_in[13];
  const float* ln2b  = (const float*)d_in[14];
  const float* Win   = (const float*)d_in[15];
  const float* bin   = (const float*)d_in[16];
  const float* Wedge = (const float*)d_in[17];
  const float* bedge = (const float*)d_in[18];
  const float* Wgate = (const float*)d_in[19];
  const float* bgate = (const float*)d_in[20];
  const float* lnfw  = (const float*)d_in[21];
  const float* lnfb  = (const float*)d_in[22];
  const float* Whead = (const float*)d_in[23];
  float* out = (float*)d_out;

  char* ws = (char*)d_ws;
  size_t off = 0;
  auto alloc = [&](size_t bytes) {
    void* p = ws + off;
    off = (off + bytes + 255) & ~(size_t)255;
    return p;
  };
  short* wtq    = (short*)alloc((size_t)L_ * D_ * D_ * 2);
  short* wtk    = (short*)alloc((size_t)L_ * D_ * D_ * 2);
  short* wtv    = (short*)alloc((size_t)L_ * D_ * D_ * 2);
  short* wto    = (short*)alloc((size_t)L_ * D_ * D_ * 2);
  short* wtin   = (short*)alloc((size_t)L_ * D_ * D_ * 2);
  short* wtgate = (short*)alloc((size_t)L_ * D_ * D_ * 2);
  short* wtedge = (short*)alloc((size_t)L_ * 2 * D_ * D_ * 2);
  short* wthead = (short*)alloc((size_t)V_ * D_ * 2);
  float* hbuf   = (float*)alloc((size_t)M_ * D_ * 4);
  short* xb     = (short*)alloc((size_t)M_ * D_ * 2);
  float* qb     = (float*)alloc((size_t)M_ * D_ * 4);
  float* kbuf   = (float*)alloc((size_t)M_ * D_ * 4);
  float* vbuf   = (float*)alloc((size_t)M_ * D_ * 4);
  short* avb    = (short*)alloc((size_t)M_ * D_ * 2);
  float* tbuf   = (float*)alloc((size_t)M_ * D_ * 4);
  short* tbf    = (short*)alloc((size_t)M_ * D_ * 2);
  short* msgb   = (short*)alloc((size_t)M_ * D_ * 2);
  (void)ws_size; (void)in_sizes; (void)n_in; (void)out_size;

  dim3 tblk(32, 8);
  transpose_cvt<<<dim3(16, 16, L_), tblk, 0, stream>>>(Wq, wtq, D_, D_);
  transpose_cvt<<<dim3(16, 16, L_), tblk, 0, stream>>>(Wk, wtk, D_, D_);
  transpose_cvt<<<dim3(16, 16, L_), tblk, 0, stream>>>(Wv, wtv, D_, D_);
  transpose_cvt<<<dim3(16, 16, L_), tblk, 0, stream>>>(Wo, wto, D_, D_);
  transpose_cvt<<<dim3(16, 16, L_), tblk, 0, stream>>>(Win, wtin, D_, D_);
  transpose_cvt<<<dim3(16, 16, L_), tblk, 0, stream>>>(Wgate, wtgate, D_, D_);
  transpose_cvt<<<dim3(16, 32, L_), tblk, 0, stream>>>(Wedge, wtedge, 2 * D_, D_);
  transpose_cvt<<<dim3(V_ / 32, 16, 1), tblk, 0, stream>>>(Whead, wthead, D_, V_);

  embed_k<<<M_, 256, 0, stream>>>(ids, tok, pos, hbuf);

  dim3 gsmall(D_ / 64, M_ / 64);   // (8,64)
  for (int l = 0; l < L_; ++l) {
    size_t wofs = (size_t)l * D_ * D_;
    ln_k<<<M_, 256, 0, stream>>>(hbuf, ln1w + l * D_, ln1b + l * D_, xb);
    gemm_k<0,0><<<gsmall, 256, 0, stream>>>(xb, wtq + wofs, bq + l * D_, qb, nullptr, nullptr, M_, D_, D_);
    gemm_k<0,0><<<gsmall, 256, 0, stream>>>(xb, wtk + wofs, bk + l * D_, kbuf, nullptr, nullptr, M_, D_, D_);
    gemm_k<0,0><<<gsmall, 256, 0, stream>>>(xb, wtv + wofs, bv + l * D_, vbuf, nullptr, nullptr, M_, D_, D_);
    attn_k<<<B_ * H_ * S_ / 4, 256, 0, stream>>>(qb, kbuf, vbuf, avb);
    gemm_k<0,1><<<gsmall, 256, 0, stream>>>(avb, wto + wofs, bo + l * D_, hbuf, nullptr, nullptr, M_, D_, D_);
    ln_k<<<M_, 256, 0, stream>>>(hbuf, ln2w + l * D_, ln2b + l * D_, xb);
    gemm_k<0,0><<<gsmall, 256, 0, stream>>>(xb, wtin + wofs, bin + l * D_, tbuf, tbf, nullptr, M_, D_, D_);
    for (int it = 0; it < 2; ++it) {
      gemm_k<1,2><<<gsmall, 256, 0, stream>>>(tbf, wtedge + (size_t)l * 2 * D_ * D_, bedge + l * D_,
                                              nullptr, msgb, nullptr, M_, D_, 2 * D_);
      gemm_k<2,3><<<gsmall, 256, 0, stream>>>(msgb, wtgate + wofs, bgate + l * D_,
                                              tbuf, tbf, msgb, M_, D_, D_);
    }
    add_k<<<(M_ * D_ / 4 + 255) / 256, 256, 0, stream>>>(hbuf, tbuf, M_ * D_ / 4);
  }
  ln_k<<<M_, 256, 0, stream>>>(hbuf, lnfw, lnfb, xb);
  gemm_k<0,0><<<dim3(V_ / 64, M_ / 64), 256, 0, stream>>>(xb, wthead, nullptr, out,
                                                          nullptr, nullptr, M_, V_, D_);
}

// Round 2
// 1495.009 us; speedup vs baseline: 4.2939x; 4.2939x over previous
//
#include <hip/hip_runtime.h>
#include <hip/hip_bf16.h>
#include <stdint.h>

#define V_ 32000
#define D_ 512
#define H_ 8
#define L_ 6
#define S_ 1024
#define B_ 4
#define DH_ 64
#define M_ (B_*S_)   // 4096

typedef __attribute__((ext_vector_type(8))) short bf16x8;
typedef __attribute__((ext_vector_type(4))) float f32x4;

__device__ __forceinline__ short f2bs(float f) {
  union { float f; uint32_t u; } x; x.f = f;
  uint32_t r = (x.u + 0x7FFFu + ((x.u >> 16) & 1u)) >> 16;
  return (short)r;
}
__device__ __forceinline__ float bs2f(short s) {
  union { uint32_t u; float f; } x; x.u = ((uint32_t)(uint16_t)s) << 16;
  return x.f;
}

__device__ __forceinline__ f32x4 mfma16(bf16x8 a, bf16x8 b, f32x4 c) {
  return __builtin_amdgcn_mfma_f32_16x16x32_bf16(a, b, c, 0, 0, 0);
}

// ---- transpose + fp32->bf16 convert: out[n*K+k] = in[k*N+n], per blockIdx.z slab ----
__global__ __launch_bounds__(256) void transpose_cvt(const float* __restrict__ in,
    short* __restrict__ out, int K, int N) {
  __shared__ float tile[32][33];
  const float* inp = in + (size_t)blockIdx.z * K * N;
  short* outp = out + (size_t)blockIdx.z * K * N;
  int kb = blockIdx.y * 32, nb = blockIdx.x * 32;
  int tx = threadIdx.x, ty = threadIdx.y;   // block (32,8)
  for (int r = ty; r < 32; r += 8) {
    int k = kb + r, n = nb + tx;
    tile[r][tx] = (k < K && n < N) ? inp[(size_t)k * N + n] : 0.f;
  }
  __syncthreads();
  for (int r = ty; r < 32; r += 8) {
    int n = nb + r, k = kb + tx;
    if (n < N && k < K) outp[(size_t)n * K + k] = f2bs(tile[tx][r]);
  }
}

// ---- embedding: h[bs,:] = tok_emb[ids[bs],:] + pos_emb[bs%S,:] ----
__global__ __launch_bounds__(256) void embed_k(const int* __restrict__ ids,
    const float* __restrict__ tok, const float* __restrict__ pos, float* __restrict__ h) {
  int bs = blockIdx.x;
  int tid = threadIdx.x;
  int s = bs & (S_ - 1);
  int id = ids[bs];
  float2 te = *(const float2*)(tok + (size_t)id * D_ + tid * 2);
  float2 pe = *(const float2*)(pos + (size_t)s * D_ + tid * 2);
  float2 r; r.x = te.x + pe.x; r.y = te.y + pe.y;
  *(float2*)(h + (size_t)bs * D_ + tid * 2) = r;
}

// ---- LayerNorm (one row of 512 per block) -> bf16 out ----
__global__ __launch_bounds__(256) void ln_k(const float* __restrict__ in,
    const float* __restrict__ w, const float* __restrict__ bb, short* __restrict__ outb) {
  int row = blockIdx.x, tid = threadIdx.x;
  int lane = tid & 63, wv = tid >> 6;
  const float* x = in + (size_t)row * D_;
  float2 v = *(const float2*)(x + tid * 2);
  float s = v.x + v.y;
  #pragma unroll
  for (int o = 32; o; o >>= 1) s += __shfl_xor(s, o);
  __shared__ float red[8];
  if (lane == 0) red[wv] = s;
  __syncthreads();
  float mu = (red[0] + red[1] + red[2] + red[3]) * (1.f / D_);
  float dx = v.x - mu, dy = v.y - mu;
  float s2 = dx * dx + dy * dy;
  #pragma unroll
  for (int o = 32; o; o >>= 1) s2 += __shfl_xor(s2, o);
  if (lane == 0) red[4 + wv] = s2;
  __syncthreads();
  float var = (red[4] + red[5] + red[6] + red[7]) * (1.f / D_);
  float rs = rsqrtf(var + 1e-5f);
  int c = tid * 2;
  float y0 = dx * rs * w[c] + bb[c];
  float y1 = dy * rs * w[c + 1] + bb[c + 1];
  short* o2 = outb + (size_t)row * D_ + c;
  o2[0] = f2bs(y0); o2[1] = f2bs(y1);
}

// ---- generic bf16 MFMA GEMM, 64x64 tile, 4 waves of 32x32 ----
// AMODE: 0 plain A[m*K+k]; 1 concat(t[m],t[m+1]) (K=1024, zero 2nd half at batch end);
//        2 shifted msg (A[m]=msg[m-1], zero at batch start)
// EMODE: 0 Cf=acc+bias (+optional bf16 Cb); 1 Cf+=acc+bias (residual);
//        2 Cb=bf16(relu(acc+bias)); 3 gate: t+=sigmoid(acc+bias)*agg, write Cf,Cb
//        4 Cb=bf16((acc+bias)*oscale) only
template<int AMODE, int EMODE>
__global__ __launch_bounds__(256) void gemm_k(
    const short* __restrict__ A, const short* __restrict__ Wt,
    const float* __restrict__ bias, float* __restrict__ Cf,
    short* __restrict__ Cb, const short* __restrict__ Agg,
    int M, int N, int K, float oscale)
{
  __shared__ short As[64][40];
  __shared__ short Bs[64][40];
  int tid = threadIdx.x;
  int m0 = blockIdx.y * 64, n0 = blockIdx.x * 64;
  int lane = tid & 63, w = tid >> 6;
  int wm = (w >> 1) * 32, wn = (w & 1) * 32;
  int l15 = lane & 15, l4 = lane >> 4;
  f32x4 acc[2][2] = {};
  int ar = tid >> 2, ac = (tid & 3) * 8;
  int gm = m0 + ar;
  const uint4 zz = make_uint4(0u, 0u, 0u, 0u);
  for (int k0 = 0; k0 < K; k0 += 32) {
    int gk = k0 + ac;
    uint4 av, bvv;
    if (AMODE == 0) {
      av = *(const uint4*)(A + (size_t)gm * K + gk);
    } else if (AMODE == 1) {
      if (gk < D_) av = *(const uint4*)(A + (size_t)gm * D_ + gk);
      else if ((gm & (S_ - 1)) == S_ - 1) av = zz;
      else av = *(const uint4*)(A + (size_t)(gm + 1) * D_ + (gk - D_));
    } else {
      if ((gm & (S_ - 1)) == 0) av = zz;
      else av = *(const uint4*)(A + (size_t)(gm - 1) * D_ + gk);
    }
    bvv = *(const uint4*)(Wt + (size_t)(n0 + ar) * K + gk);
    __syncthreads();
    *(uint4*)&As[ar][ac] = av;
    *(uint4*)&Bs[ar][ac] = bvv;
    __syncthreads();
    bf16x8 a0 = *(const bf16x8*)&As[wm + l15][l4 * 8];
    bf16x8 a1 = *(const bf16x8*)&As[wm + 16 + l15][l4 * 8];
    bf16x8 b0 = *(const bf16x8*)&Bs[wn + l15][l4 * 8];
    bf16x8 b1 = *(const bf16x8*)&Bs[wn + 16 + l15][l4 * 8];
    acc[0][0] = mfma16(a0, b0, acc[0][0]);
    acc[0][1] = mfma16(a0, b1, acc[0][1]);
    acc[1][0] = mfma16(a1, b0, acc[1][0]);
    acc[1][1] = mfma16(a1, b1, acc[1][1]);
  }
  int rowb = m0 + wm + l4 * 4;
  int colb = n0 + wn + l15;
  #pragma unroll
  for (int fm = 0; fm < 2; ++fm) {
    #pragma unroll
    for (int fn = 0; fn < 2; ++fn) {
      int col = colb + fn * 16;
      float bias_v = bias ? bias[col] : 0.f;
      #pragma unroll
      for (int r = 0; r < 4; ++r) {
        int row = rowb + fm * 16 + r;
        size_t idx = (size_t)row * N + col;
        float v = acc[fm][fn][r] + bias_v;
        if (EMODE == 0) {
          Cf[idx] = v;
          if (Cb) Cb[idx] = f2bs(v);
        } else if (EMODE == 1) {
          Cf[idx] += v;
        } else if (EMODE == 2) {
          v = fmaxf(v, 0.f);
          Cb[idx] = f2bs(v);
        } else if (EMODE == 3) {
          float g = 1.f / (1.f + __expf(-v));
          float aggv = ((row & (S_ - 1)) == 0) ? 0.f : bs2f(Agg[(size_t)(row - 1) * N + col]);
          float tn = Cf[idx] + g * aggv;
          Cf[idx] = tn;
          Cb[idx] = f2bs(tn);
        } else {
          Cb[idx] = f2bs(v * oscale);
        }
      }
    }
  }
}

// ---- flash attention, MFMA 16x16x32, 64-query tile per block, 4 waves x 16 rows ----
// Q pre-scaled by 1/sqrt(DH). Layout of Q/K/V/out: [b*S + s][D] bf16, head slice h*64.
__global__ __launch_bounds__(256) void fattn_k(const short* __restrict__ Qb,
    const short* __restrict__ Kb, const short* __restrict__ Vb, short* __restrict__ avb)
{
  __shared__ short Ks[64][72];        // [key][dh]
  __shared__ short Vt[64][72];        // [dh][key^swz]
  __shared__ short Ps[4][16][72];     // per-wave P [q][key]
  int tid = threadIdx.x, lane = tid & 63, w = tid >> 6;
  int bx = blockIdx.x;
  int qt = 15 - (bx >> 5);            // heavy tiles first
  int bh = bx & 31, b = bh >> 3, hh = bh & 7;
  int l15 = lane & 15, g = lane >> 4;

  // Q fragments (A-operand): row = l15, k = kk*32 + g*8 + j
  int qrow = qt * 64 + w * 16 + l15;
  const short* qptr = Qb + (size_t)(b * S_ + qrow) * D_ + hh * DH_;
  uint4 qa0 = *(const uint4*)(qptr + g * 8);
  uint4 qa1 = *(const uint4*)(qptr + 32 + g * 8);

  f32x4 o[4] = {};
  float mrow[4], lrow[4];
  #pragma unroll
  for (int r = 0; r < 4; ++r) { mrow[r] = -1e30f; lrow[r] = 0.f; }

  int ntiles = qt + 1;
  for (int kt = 0; kt < ntiles; ++kt) {
    int key0 = kt * 64;
    __syncthreads();   // prev-iter LDS reads done
    #pragma unroll
    for (int i = 0; i < 2; ++i) {
      int c = tid + i * 256;
      int key = c >> 3, d0 = (c & 7) * 8;
      const short* kvp = Kb + (size_t)(b * S_ + key0 + key) * D_ + hh * DH_ + d0;
      const short* vvp = Vb + (size_t)(b * S_ + key0 + key) * D_ + hh * DH_ + d0;
      uint4 kv = *(const uint4*)kvp;
      uint4 vv = *(const uint4*)vvp;
      *(uint4*)&Ks[key][d0] = kv;
      short vs[8]; *(uint4*)vs = vv;
      int a = (c & 7);
      #pragma unroll
      for (int j = 0; j < 8; ++j)
        Vt[d0 + j][key ^ (a << 3)] = vs[j];   // swz: col = key ^ (((dim>>3)&7)<<3)
    }
    __syncthreads();

    // S = Q K^T  (rows g*4+r, cols f*16+l15)
    f32x4 sc[4] = {};
    #pragma unroll
    for (int f = 0; f < 4; ++f) {
      bf16x8 kb0 = *(const bf16x8*)&Ks[f * 16 + l15][g * 8];
      bf16x8 kb1 = *(const bf16x8*)&Ks[f * 16 + l15][32 + g * 8];
      sc[f] = mfma16(*(const bf16x8*)&qa0, kb0, sc[f]);
      sc[f] = mfma16(*(const bf16x8*)&qa1, kb1, sc[f]);
    }

    // online softmax per row
    float p[4][4];
    #pragma unroll
    for (int r = 0; r < 4; ++r) {
      int rowg = qt * 64 + w * 16 + g * 4 + r;
      float s0[4];
      #pragma unroll
      for (int f = 0; f < 4; ++f) {
        int keyg = key0 + f * 16 + l15;
        s0[f] = (keyg <= rowg) ? sc[f][r] : -1e30f;
      }
      float cm = fmaxf(fmaxf(s0[0], s0[1]), fmaxf(s0[2], s0[3]));
      #pragma unroll
      for (int ofs = 1; ofs < 16; ofs <<= 1) cm = fmaxf(cm, __shfl_xor(cm, ofs));
      float mn = fmaxf(mrow[r], cm);
      float fr = __expf(mrow[r] - mn);
      mrow[r] = mn;
      float ss = 0.f;
      #pragma unroll
      for (int f = 0; f < 4; ++f) { float e = __expf(s0[f] - mn); p[f][r] = e; ss += e; }
      #pragma unroll
      for (int ofs = 1; ofs < 16; ofs <<= 1) ss += __shfl_xor(ss, ofs);
      lrow[r] = lrow[r] * fr + ss;
      #pragma unroll
      for (int nt = 0; nt < 4; ++nt) o[nt][r] *= fr;
    }

    // P -> LDS (per-wave private; within-wave dependency, no barrier)
    #pragma unroll
    for (int f = 0; f < 4; ++f)
      #pragma unroll
      for (int r = 0; r < 4; ++r)
        Ps[w][g * 4 + r][f * 16 + l15] = f2bs(p[f][r]);

    // O += P V : A = P (rows l15, k = keys), B = V^T
    bf16x8 pa0 = *(const bf16x8*)&Ps[w][l15][g * 8];
    bf16x8 pa1 = *(const bf16x8*)&Ps[w][l15][32 + g * 8];
    #pragma unroll
    for (int nt = 0; nt < 4; ++nt) {
      int dim = nt * 16 + l15;
      int vswz = ((dim >> 3) & 7) << 3;
      bf16x8 vb0 = *(const bf16x8*)&Vt[dim][(g * 8) ^ vswz];
      bf16x8 vb1 = *(const bf16x8*)&Vt[dim][(32 + g * 8) ^ vswz];
      o[nt] = mfma16(pa0, vb0, o[nt]);
      o[nt] = mfma16(pa1, vb1, o[nt]);
    }
  }

  #pragma unroll
  for (int r = 0; r < 4; ++r) {
    float inv = 1.f / lrow[r];
    int rowg = qt * 64 + w * 16 + g * 4 + r;
    short* op = avb + (size_t)(b * S_ + rowg) * D_ + hh * DH_;
    #pragma unroll
    for (int nt = 0; nt < 4; ++nt)
      op[nt * 16 + l15] = f2bs(o[nt][r] * inv);
  }
}

// ---- h += t ----
__global__ __launch_bounds__(256) void add_k(float* __restrict__ h,
    const float* __restrict__ t, int n4) {
  int i = blockIdx.x * 256 + threadIdx.x;
  if (i < n4) {
    float4 a = ((const float4*)h)[i];
    float4 c = ((const float4*)t)[i];
    a.x += c.x; a.y += c.y; a.z += c.z; a.w += c.w;
    ((float4*)h)[i] = a;
  }
}

extern "C" void kernel_launch(void* const* d_in, const int* in_sizes, int n_in,
                              void* d_out, int out_size, void* d_ws, size_t ws_size,
                              hipStream_t stream) {
  const int*   ids   = (const int*)d_in[0];
  const float* tok   = (const float*)d_in[1];
  const float* pos   = (const float*)d_in[2];
  const float* Wq    = (const float*)d_in[3];
  const float* bq    = (const float*)d_in[4];
  const float* Wk    = (const float*)d_in[5];
  const float* bk    = (const float*)d_in[6];
  const float* Wv    = (const float*)d_in[7];
  const float* bv    = (const float*)d_in[8];
  const float* Wo    = (const float*)d_in[9];
  const float* bo    = (const float*)d_in[10];
  const float* ln1w  = (const float*)d_in[11];
  const float* ln1b  = (const float*)d_in[12];
  const float* ln2w  = (const float*)d_in[13];
  const float* ln2b  = (const float*)d_in[14];
  const float* Win   = (const float*)d_in[15];
  const float* bin   = (const float*)d_in[16];
  const float* Wedge = (const float*)d_in[17];
  const float* bedge = (const float*)d_in[18];
  const float* Wgate = (const float*)d_in[19];
  const float* bgate = (const float*)d_in[20];
  const float* lnfw  = (const float*)d_in[21];
  const float* lnfb  = (const float*)d_in[22];
  const float* Whead = (const float*)d_in[23];
  float* out = (float*)d_out;

  char* ws = (char*)d_ws;
  size_t off = 0;
  auto alloc = [&](size_t bytes) {
    void* p = ws + off;
    off = (off + bytes + 255) & ~(size_t)255;
    return p;
  };
  short* wtq    = (short*)alloc((size_t)L_ * D_ * D_ * 2);
  short* wtk    = (short*)alloc((size_t)L_ * D_ * D_ * 2);
  short* wtv    = (short*)alloc((size_t)L_ * D_ * D_ * 2);
  short* wto    = (short*)alloc((size_t)L_ * D_ * D_ * 2);
  short* wtin   = (short*)alloc((size_t)L_ * D_ * D_ * 2);
  short* wtgate = (short*)alloc((size_t)L_ * D_ * D_ * 2);
  short* wtedge = (short*)alloc((size_t)L_ * 2 * D_ * D_ * 2);
  short* wthead = (short*)alloc((size_t)V_ * D_ * 2);
  float* hbuf   = (float*)alloc((size_t)M_ * D_ * 4);
  short* xb     = (short*)alloc((size_t)M_ * D_ * 2);
  short* qbb    = (short*)alloc((size_t)M_ * D_ * 2);
  short* kbb    = (short*)alloc((size_t)M_ * D_ * 2);
  short* vbb    = (short*)alloc((size_t)M_ * D_ * 2);
  short* avb    = (short*)alloc((size_t)M_ * D_ * 2);
  float* tbuf   = (float*)alloc((size_t)M_ * D_ * 4);
  short* tbf    = (short*)alloc((size_t)M_ * D_ * 2);
  short* msgb   = (short*)alloc((size_t)M_ * D_ * 2);
  (void)ws_size; (void)in_sizes; (void)n_in; (void)out_size;

  dim3 tblk(32, 8);
  transpose_cvt<<<dim3(16, 16, L_), tblk, 0, stream>>>(Wq, wtq, D_, D_);
  transpose_cvt<<<dim3(16, 16, L_), tblk, 0, stream>>>(Wk, wtk, D_, D_);
  transpose_cvt<<<dim3(16, 16, L_), tblk, 0, stream>>>(Wv, wtv, D_, D_);
  transpose_cvt<<<dim3(16, 16, L_), tblk, 0, stream>>>(Wo, wto, D_, D_);
  transpose_cvt<<<dim3(16, 16, L_), tblk, 0, stream>>>(Win, wtin, D_, D_);
  transpose_cvt<<<dim3(16, 16, L_), tblk, 0, stream>>>(Wgate, wtgate, D_, D_);
  transpose_cvt<<<dim3(16, 32, L_), tblk, 0, stream>>>(Wedge, wtedge, 2 * D_, D_);
  transpose_cvt<<<dim3(V_ / 32, 16, 1), tblk, 0, stream>>>(Whead, wthead, D_, V_);

  embed_k<<<M_, 256, 0, stream>>>(ids, tok, pos, hbuf);

  dim3 gsmall(D_ / 64, M_ / 64);   // (8,64)
  for (int l = 0; l < L_; ++l) {
    size_t wofs = (size_t)l * D_ * D_;
    ln_k<<<M_, 256, 0, stream>>>(hbuf, ln1w + l * D_, ln1b + l * D_, xb);
    gemm_k<0,4><<<gsmall, 256, 0, stream>>>(xb, wtq + wofs, bq + l * D_, nullptr, qbb, nullptr, M_, D_, D_, 0.125f);
    gemm_k<0,4><<<gsmall, 256, 0, stream>>>(xb, wtk + wofs, bk + l * D_, nullptr, kbb, nullptr, M_, D_, D_, 1.f);
    gemm_k<0,4><<<gsmall, 256, 0, stream>>>(xb, wtv + wofs, bv + l * D_, nullptr, vbb, nullptr, M_, D_, D_, 1.f);
    fattn_k<<<B_ * H_ * (S_ / 64), 256, 0, stream>>>(qbb, kbb, vbb, avb);
    gemm_k<0,1><<<gsmall, 256, 0, stream>>>(avb, wto + wofs, bo + l * D_, hbuf, nullptr, nullptr, M_, D_, D_, 1.f);
    ln_k<<<M_, 256, 0, stream>>>(hbuf, ln2w + l * D_, ln2b + l * D_, xb);
    gemm_k<0,0><<<gsmall, 256, 0, stream>>>(xb, wtin + wofs, bin + l * D_, tbuf, tbf, nullptr, M_, D_, D_, 1.f);
    for (int it = 0; it < 2; ++it) {
      gemm_k<1,2><<<gsmall, 256, 0, stream>>>(tbf, wtedge + (size_t)l * 2 * D_ * D_, bedge + l * D_,
                                              nullptr, msgb, nullptr, M_, D_, 2 * D_, 1.f);
      gemm_k<2,3><<<gsmall, 256, 0, stream>>>(msgb, wtgate + wofs, bgate + l * D_,
                                              tbuf, tbf, msgb, M_, D_, D_, 1.f);
    }
    add_k<<<(M_ * D_ / 4 + 255) / 256, 256, 0, stream>>>(hbuf, tbuf, M_ * D_ / 4);
  }
  ln_k<<<M_, 256, 0, stream>>>(hbuf, lnfw, lnfb, xb);
  gemm_k<0,0><<<dim3(V_ / 64, M_ / 64), 256, 0, stream>>>(xb, wthead, nullptr, out,
                                                          nullptr, nullptr, M_, V_, D_, 1.f);
}

// Round 3
// 1406.035 us; speedup vs baseline: 4.5656x; 1.0633x over previous
//
#include <hip/hip_runtime.h>
#include <hip/hip_bf16.h>
#include <stdint.h>

#define V_ 32000
#define D_ 512
#define H_ 8
#define L_ 6
#define S_ 1024
#define B_ 4
#define DH_ 64
#define M_ (B_*S_)   // 4096

typedef __attribute__((ext_vector_type(8))) short bf16x8;
typedef __attribute__((ext_vector_type(4))) float f32x4;

__device__ __forceinline__ short f2bs(float f) {
  union { float f; uint32_t u; } x; x.f = f;
  uint32_t r = (x.u + 0x7FFFu + ((x.u >> 16) & 1u)) >> 16;
  return (short)r;
}
__device__ __forceinline__ float bs2f(short s) {
  union { uint32_t u; float f; } x; x.u = ((uint32_t)(uint16_t)s) << 16;
  return x.f;
}

__device__ __forceinline__ f32x4 mfma16(bf16x8 a, bf16x8 b, f32x4 c) {
  return __builtin_amdgcn_mfma_f32_16x16x32_bf16(a, b, c, 0, 0, 0);
}

// async global->LDS, 16B per lane; LDS dest = wave-uniform base + lane*16
__device__ __forceinline__ void gload16(const short* g, char* lds) {
  __builtin_amdgcn_global_load_lds(
      (const __attribute__((address_space(1))) uint32_t*)g,
      (__attribute__((address_space(3))) uint32_t*)lds, 16, 0, 0);
}

// ---- transpose + fp32->bf16 convert: out[(orow0+n)*K + k] = in[k*N+n] ----
__global__ __launch_bounds__(256) void transpose_cvt(const float* __restrict__ in,
    short* __restrict__ out, int K, int N, size_t in_slab, size_t out_slab, int orow0) {
  __shared__ float tile[32][33];
  const float* inp = in + (size_t)blockIdx.z * in_slab;
  short* outp = out + (size_t)blockIdx.z * out_slab;
  int kb = blockIdx.y * 32, nb = blockIdx.x * 32;
  int tx = threadIdx.x, ty = threadIdx.y;   // block (32,8)
  for (int r = ty; r < 32; r += 8) {
    int k = kb + r, n = nb + tx;
    tile[r][tx] = (k < K && n < N) ? inp[(size_t)k * N + n] : 0.f;
  }
  __syncthreads();
  for (int r = ty; r < 32; r += 8) {
    int n = nb + r, k = kb + tx;
    if (n < N && k < K) outp[(size_t)(orow0 + n) * K + k] = f2bs(tile[tx][r]);
  }
}

__global__ __launch_bounds__(256) void pack_qkv_bias(const float* __restrict__ bq,
    const float* __restrict__ bk, const float* __restrict__ bv, float* __restrict__ o) {
  int i = blockIdx.x * 256 + threadIdx.x;   // < L_*1536
  int l = i / 1536, c = i - l * 1536;
  float v = (c < 512) ? bq[l * 512 + c] : (c < 1024) ? bk[l * 512 + c - 512]
                                                     : bv[l * 512 + c - 1024];
  o[i] = v;
}

// ---- embedding ----
__global__ __launch_bounds__(256) void embed_k(const int* __restrict__ ids,
    const float* __restrict__ tok, const float* __restrict__ pos, float* __restrict__ h) {
  int bs = blockIdx.x;
  int tid = threadIdx.x;
  int s = bs & (S_ - 1);
  int id = ids[bs];
  float2 te = *(const float2*)(tok + (size_t)id * D_ + tid * 2);
  float2 pe = *(const float2*)(pos + (size_t)s * D_ + tid * 2);
  float2 r; r.x = te.x + pe.x; r.y = te.y + pe.y;
  *(float2*)(h + (size_t)bs * D_ + tid * 2) = r;
}

// ---- LayerNorm -> bf16 ----
__global__ __launch_bounds__(256) void ln_k(const float* __restrict__ in,
    const float* __restrict__ w, const float* __restrict__ bb, short* __restrict__ outb) {
  int row = blockIdx.x, tid = threadIdx.x;
  int lane = tid & 63, wv = tid >> 6;
  const float* x = in + (size_t)row * D_;
  float2 v = *(const float2*)(x + tid * 2);
  float s = v.x + v.y;
  #pragma unroll
  for (int o = 32; o; o >>= 1) s += __shfl_xor(s, o);
  __shared__ float red[8];
  if (lane == 0) red[wv] = s;
  __syncthreads();
  float mu = (red[0] + red[1] + red[2] + red[3]) * (1.f / D_);
  float dx = v.x - mu, dy = v.y - mu;
  float s2 = dx * dx + dy * dy;
  #pragma unroll
  for (int o = 32; o; o >>= 1) s2 += __shfl_xor(s2, o);
  if (lane == 0) red[4 + wv] = s2;
  __syncthreads();
  float var = (red[4] + red[5] + red[6] + red[7]) * (1.f / D_);
  float rs = rsqrtf(var + 1e-5f);
  int c = tid * 2;
  float y0 = dx * rs * w[c] + bb[c];
  float y1 = dy * rs * w[c + 1] + bb[c + 1];
  short* o2 = outb + (size_t)row * D_ + c;
  o2[0] = f2bs(y0); o2[1] = f2bs(y1);
}

// ================= 128xBN MFMA GEMM, global_load_lds + XOR-swizzled LDS =========
// A logical: [M][K] bf16 (AMODE=0, row-stride K); AMODE=1: concat(t[m],t[m+1]),
// t row-stride D_, zeros for m%S==S-1 upper half; AMODE=2: A[m]=msg[m-1], zeros m%S==0.
// LDS: linear [rows][32] bf16 (64B row stride); element at (row, kel) stored at
// byte row*64 + (kel*2 ^ ((row&6)<<3)) -- staged by pre-swizzling the GLOBAL source
// (rule 21: both-sides-or-neither), read back with the same XOR.
// EMODE: 0 Cf=acc+b (+Cb bf16 if nonnull); 1 Cf+=; 2 Cb=relu; 3 gate-iter0;
//        5 gate-iter1 fused residual (Hf += Cf + sig*agg); 4 QKV bf16 (q cols scaled)
template<int AMODE, int EMODE, int BN>
__global__ __launch_bounds__(256) void gemm2_k(
    const short* __restrict__ A, const short* __restrict__ Wt,
    const float* __restrict__ bias, float* __restrict__ Cf,
    short* __restrict__ Cb, const short* __restrict__ Agg,
    float* __restrict__ Hf, const short* __restrict__ zpad,
    int M, int N, int K)
{
  constexpr int NF = BN / 32;              // B-frags per wave
  __shared__ __align__(16) char As[128 * 64];
  __shared__ __align__(16) char Bs[BN * 64];
  const int tid = threadIdx.x;
  const int lane = tid & 63, w = tid >> 6;
  const int m0 = blockIdx.y * 128, n0 = blockIdx.x * BN;
  const int l15 = lane & 15, l4 = lane >> 4;
  const int wm = (w >> 1) * 64, wn = (w & 1) * (BN / 2);

  // ---- staging source addresses (pre-swizzled globals) ----
  const int srow = tid >> 2;                       // 0..63, +64 on round 1
  const short* agp[2];
  const short* agpHi[2];
  #pragma unroll
  for (int r = 0; r < 2; ++r) {
    int lrow = srow + r * 64;
    int row = m0 + lrow;
    int kel = ((tid & 3) * 8) ^ ((lrow & 6) << 2);
    if (AMODE == 0) {
      agp[r] = A + (size_t)row * K + kel;
    } else if (AMODE == 1) {
      agp[r]   = A + (size_t)row * D_ + kel;
      agpHi[r] = ((row & (S_ - 1)) == (S_ - 1)) ? zpad + kel
                                                : A + (size_t)(row + 1) * D_ + kel;
    } else {
      agp[r] = ((row & (S_ - 1)) == 0) ? zpad + kel : A + (size_t)(row - 1) * D_ + kel;
    }
  }
  constexpr int BR = BN / 64;                      // B staging rounds
  const short* bgp[BR];
  #pragma unroll
  for (int r = 0; r < BR; ++r) {
    int lrow = srow + r * 64;
    int kel = ((tid & 3) * 8) ^ ((lrow & 6) << 2);
    bgp[r] = Wt + (size_t)(n0 + lrow) * K + kel;
  }

  // ---- fragment read byte-offsets (swizzle depends only on l15 bits 1-2) ----
  const int rswz = (l15 & 6) << 3;
  const int cb = (l4 * 16) ^ rswz;
  int aoff[4], boff[NF];
  #pragma unroll
  for (int i = 0; i < 4; ++i) aoff[i] = (wm + i * 16 + l15) * 64 + cb;
  #pragma unroll
  for (int j = 0; j < NF; ++j) boff[j] = (wn + j * 16 + l15) * 64 + cb;

  f32x4 acc[4][NF] = {};

  for (int k0 = 0; k0 < K; k0 += 32) {
    __syncthreads();
    #pragma unroll
    for (int r = 0; r < 2; ++r) {
      const short* gp;
      if (AMODE == 1) gp = (k0 < D_) ? agp[r] + k0 : agpHi[r] + (k0 - D_);
      else gp = agp[r] + k0;
      gload16(gp, As + r * 4096 + w * 1024);
    }
    #pragma unroll
    for (int r = 0; r < BR; ++r)
      gload16(bgp[r] + k0, Bs + r * 4096 + w * 1024);
    asm volatile("s_waitcnt vmcnt(0)" ::: "memory");
    __syncthreads();
    bf16x8 af[4], bfr[NF];
    #pragma unroll
    for (int i = 0; i < 4; ++i) af[i] = *(const bf16x8*)(As + aoff[i]);
    #pragma unroll
    for (int j = 0; j < NF; ++j) bfr[j] = *(const bf16x8*)(Bs + boff[j]);
    #pragma unroll
    for (int i = 0; i < 4; ++i)
      #pragma unroll
      for (int j = 0; j < NF; ++j)
        acc[i][j] = mfma16(af[i], bfr[j], acc[i][j]);
  }

  const int rowb = m0 + wm + l4 * 4;
  const int colb = n0 + wn + l15;
  #pragma unroll
  for (int i = 0; i < 4; ++i) {
    #pragma unroll
    for (int j = 0; j < NF; ++j) {
      int col = colb + j * 16;
      float bias_v = bias ? bias[col] : 0.f;
      #pragma unroll
      for (int r = 0; r < 4; ++r) {
        int row = rowb + i * 16 + r;
        size_t idx = (size_t)row * N + col;
        float v = acc[i][j][r] + bias_v;
        if (EMODE == 0) {
          Cf[idx] = v;
          if (Cb) Cb[idx] = f2bs(v);
        } else if (EMODE == 1) {
          Cf[idx] += v;
        } else if (EMODE == 2) {
          Cb[idx] = f2bs(fmaxf(v, 0.f));
        } else if (EMODE == 3) {
          float g = 1.f / (1.f + __expf(-v));
          float aggv = ((row & (S_ - 1)) == 0) ? 0.f : bs2f(Agg[idx - N]);
          float tn = Cf[idx] + g * aggv;
          Cf[idx] = tn; Cb[idx] = f2bs(tn);
        } else if (EMODE == 5) {
          float g = 1.f / (1.f + __expf(-v));
          float aggv = ((row & (S_ - 1)) == 0) ? 0.f : bs2f(Agg[idx - N]);
          Hf[idx] += Cf[idx] + g * aggv;
        } else {   // 4: QKV packed bf16, q-scale on first D_ cols
          float sc = (col < D_) ? 0.125f : 1.f;
          Cb[idx] = f2bs(v * sc);
        }
      }
    }
  }
}

// ---- flash attention on packed QKV [M][3*D_] bf16; Q pre-scaled ----
__global__ __launch_bounds__(256) void fattn_k(const short* __restrict__ Qkv,
    short* __restrict__ avb)
{
  __shared__ short Ks[64][72];
  __shared__ short Vt[64][72];
  __shared__ short Ps[4][16][72];
  const int QS = 3 * D_;
  int tid = threadIdx.x, lane = tid & 63, w = tid >> 6;
  int bx = blockIdx.x;
  int qt = 15 - (bx >> 5);
  int bh = bx & 31, b = bh >> 3, hh = bh & 7;
  int l15 = lane & 15, g = lane >> 4;

  int qrow = qt * 64 + w * 16 + l15;
  const short* qptr = Qkv + (size_t)(b * S_ + qrow) * QS + hh * DH_;
  uint4 qa0 = *(const uint4*)(qptr + g * 8);
  uint4 qa1 = *(const uint4*)(qptr + 32 + g * 8);

  f32x4 o[4] = {};
  float mrow[4], lrow[4];
  #pragma unroll
  for (int r = 0; r < 4; ++r) { mrow[r] = -1e30f; lrow[r] = 0.f; }

  int ntiles = qt + 1;
  for (int kt = 0; kt < ntiles; ++kt) {
    int key0 = kt * 64;
    __syncthreads();
    #pragma unroll
    for (int i = 0; i < 2; ++i) {
      int c = tid + i * 256;
      int key = c >> 3, d0 = (c & 7) * 8;
      const short* base = Qkv + (size_t)(b * S_ + key0 + key) * QS + hh * DH_ + d0;
      uint4 kv = *(const uint4*)(base + D_);
      uint4 vv = *(const uint4*)(base + 2 * D_);
      *(uint4*)&Ks[key][d0] = kv;
      short vs[8]; *(uint4*)vs = vv;
      int a = (c & 7);
      #pragma unroll
      for (int j = 0; j < 8; ++j)
        Vt[d0 + j][key ^ (a << 3)] = vs[j];
    }
    __syncthreads();

    f32x4 sc[4] = {};
    #pragma unroll
    for (int f = 0; f < 4; ++f) {
      bf16x8 kb0 = *(const bf16x8*)&Ks[f * 16 + l15][g * 8];
      bf16x8 kb1 = *(const bf16x8*)&Ks[f * 16 + l15][32 + g * 8];
      sc[f] = mfma16(*(const bf16x8*)&qa0, kb0, sc[f]);
      sc[f] = mfma16(*(const bf16x8*)&qa1, kb1, sc[f]);
    }

    float p[4][4];
    #pragma unroll
    for (int r = 0; r < 4; ++r) {
      int rowg = qt * 64 + w * 16 + g * 4 + r;
      float s0[4];
      #pragma unroll
      for (int f = 0; f < 4; ++f) {
        int keyg = key0 + f * 16 + l15;
        s0[f] = (keyg <= rowg) ? sc[f][r] : -1e30f;
      }
      float cm = fmaxf(fmaxf(s0[0], s0[1]), fmaxf(s0[2], s0[3]));
      #pragma unroll
      for (int ofs = 1; ofs < 16; ofs <<= 1) cm = fmaxf(cm, __shfl_xor(cm, ofs));
      float mn = fmaxf(mrow[r], cm);
      float fr = __expf(mrow[r] - mn);
      mrow[r] = mn;
      float ss = 0.f;
      #pragma unroll
      for (int f = 0; f < 4; ++f) { float e = __expf(s0[f] - mn); p[f][r] = e; ss += e; }
      #pragma unroll
      for (int ofs = 1; ofs < 16; ofs <<= 1) ss += __shfl_xor(ss, ofs);
      lrow[r] = lrow[r] * fr + ss;
      #pragma unroll
      for (int nt = 0; nt < 4; ++nt) o[nt][r] *= fr;
    }

    #pragma unroll
    for (int f = 0; f < 4; ++f)
      #pragma unroll
      for (int r = 0; r < 4; ++r)
        Ps[w][g * 4 + r][f * 16 + l15] = f2bs(p[f][r]);

    bf16x8 pa0 = *(const bf16x8*)&Ps[w][l15][g * 8];
    bf16x8 pa1 = *(const bf16x8*)&Ps[w][l15][32 + g * 8];
    #pragma unroll
    for (int nt = 0; nt < 4; ++nt) {
      int dim = nt * 16 + l15;
      int vswz = ((dim >> 3) & 7) << 3;
      bf16x8 vb0 = *(const bf16x8*)&Vt[dim][(g * 8) ^ vswz];
      bf16x8 vb1 = *(const bf16x8*)&Vt[dim][(32 + g * 8) ^ vswz];
      o[nt] = mfma16(pa0, vb0, o[nt]);
      o[nt] = mfma16(pa1, vb1, o[nt]);
    }
  }

  #pragma unroll
  for (int r = 0; r < 4; ++r) {
    float inv = 1.f / lrow[r];
    int rowg = qt * 64 + w * 16 + g * 4 + r;
    short* op = avb + (size_t)(b * S_ + rowg) * D_ + hh * DH_;
    #pragma unroll
    for (int nt = 0; nt < 4; ++nt)
      op[nt * 16 + l15] = f2bs(o[nt][r] * inv);
  }
}

extern "C" void kernel_launch(void* const* d_in, const int* in_sizes, int n_in,
                              void* d_out, int out_size, void* d_ws, size_t ws_size,
                              hipStream_t stream) {
  const int*   ids   = (const int*)d_in[0];
  const float* tok   = (const float*)d_in[1];
  const float* pos   = (const float*)d_in[2];
  const float* Wq    = (const float*)d_in[3];
  const float* bq    = (const float*)d_in[4];
  const float* Wk    = (const float*)d_in[5];
  const float* bk    = (const float*)d_in[6];
  const float* Wv    = (const float*)d_in[7];
  const float* bv    = (const float*)d_in[8];
  const float* Wo    = (const float*)d_in[9];
  const float* bo    = (const float*)d_in[10];
  const float* ln1w  = (const float*)d_in[11];
  const float* ln1b  = (const float*)d_in[12];
  const float* ln2w  = (const float*)d_in[13];
  const float* ln2b  = (const float*)d_in[14];
  const float* Win   = (const float*)d_in[15];
  const float* bin   = (const float*)d_in[16];
  const float* Wedge = (const float*)d_in[17];
  const float* bedge = (const float*)d_in[18];
  const float* Wgate = (const float*)d_in[19];
  const float* bgate = (const float*)d_in[20];
  const float* lnfw  = (const float*)d_in[21];
  const float* lnfb  = (const float*)d_in[22];
  const float* Whead = (const float*)d_in[23];
  float* out = (float*)d_out;

  char* ws = (char*)d_ws;
  size_t off = 0;
  auto alloc = [&](size_t bytes) {
    void* p = ws + off;
    off = (off + bytes + 255) & ~(size_t)255;
    return p;
  };
  short* wqkv   = (short*)alloc((size_t)L_ * 3 * D_ * D_ * 2);
  float* bqkv   = (float*)alloc((size_t)L_ * 3 * D_ * 4);
  short* wto    = (short*)alloc((size_t)L_ * D_ * D_ * 2);
  short* wtin   = (short*)alloc((size_t)L_ * D_ * D_ * 2);
  short* wtgate = (short*)alloc((size_t)L_ * D_ * D_ * 2);
  short* wtedge = (short*)alloc((size_t)L_ * 2 * D_ * D_ * 2);
  short* wthead = (short*)alloc((size_t)V_ * D_ * 2);
  short* zpad   = (short*)alloc(4096);
  float* hbuf   = (float*)alloc((size_t)M_ * D_ * 4);
  short* xb     = (short*)alloc((size_t)M_ * D_ * 2);
  short* qkvb   = (short*)alloc((size_t)M_ * 3 * D_ * 2);
  short* avb    = (short*)alloc((size_t)M_ * D_ * 2);
  float* tbuf   = (float*)alloc((size_t)M_ * D_ * 4);
  short* tbf    = (short*)alloc((size_t)M_ * D_ * 2);
  short* msgb   = (short*)alloc((size_t)M_ * D_ * 2);
  (void)ws_size; (void)in_sizes; (void)n_in; (void)out_size;

  hipMemsetAsync(zpad, 0, 4096, stream);

  dim3 tblk(32, 8);
  // packed QKV weights: rows 0..511 = Wq^T, 512..1023 = Wk^T, 1024..1535 = Wv^T
  transpose_cvt<<<dim3(16, 16, L_), tblk, 0, stream>>>(Wq, wqkv, D_, D_, (size_t)D_*D_, (size_t)3*D_*D_, 0);
  transpose_cvt<<<dim3(16, 16, L_), tblk, 0, stream>>>(Wk, wqkv, D_, D_, (size_t)D_*D_, (size_t)3*D_*D_, D_);
  transpose_cvt<<<dim3(16, 16, L_), tblk, 0, stream>>>(Wv, wqkv, D_, D_, (size_t)D_*D_, (size_t)3*D_*D_, 2*D_);
  transpose_cvt<<<dim3(16, 16, L_), tblk, 0, stream>>>(Wo, wto, D_, D_, (size_t)D_*D_, (size_t)D_*D_, 0);
  transpose_cvt<<<dim3(16, 16, L_), tblk, 0, stream>>>(Win, wtin, D_, D_, (size_t)D_*D_, (size_t)D_*D_, 0);
  transpose_cvt<<<dim3(16, 16, L_), tblk, 0, stream>>>(Wgate, wtgate, D_, D_, (size_t)D_*D_, (size_t)D_*D_, 0);
  transpose_cvt<<<dim3(16, 32, L_), tblk, 0, stream>>>(Wedge, wtedge, 2*D_, D_, (size_t)2*D_*D_, (size_t)2*D_*D_, 0);
  transpose_cvt<<<dim3(V_/32, 16, 1), tblk, 0, stream>>>(Whead, wthead, D_, V_, (size_t)D_*V_, (size_t)D_*V_, 0);
  pack_qkv_bias<<<(L_ * 3 * D_) / 256, 256, 0, stream>>>(bq, bk, bv, bqkv);

  embed_k<<<M_, 256, 0, stream>>>(ids, tok, pos, hbuf);

  dim3 g64(D_ / 64, M_ / 128);        // (8,32) for BN=64, N=512
  dim3 gqkv(3 * D_ / 128, M_ / 128);  // (12,32)
  for (int l = 0; l < L_; ++l) {
    size_t wofs = (size_t)l * D_ * D_;
    ln_k<<<M_, 256, 0, stream>>>(hbuf, ln1w + l * D_, ln1b + l * D_, xb);
    gemm2_k<0,4,128><<<gqkv, 256, 0, stream>>>(xb, wqkv + (size_t)l * 3 * D_ * D_,
        bqkv + (size_t)l * 3 * D_, nullptr, qkvb, nullptr, nullptr, zpad, M_, 3 * D_, D_);
    fattn_k<<<B_ * H_ * (S_ / 64), 256, 0, stream>>>(qkvb, avb);
    gemm2_k<0,1,64><<<g64, 256, 0, stream>>>(avb, wto + wofs, bo + l * D_,
        hbuf, nullptr, nullptr, nullptr, zpad, M_, D_, D_);
    ln_k<<<M_, 256, 0, stream>>>(hbuf, ln2w + l * D_, ln2b + l * D_, xb);
    gemm2_k<0,0,64><<<g64, 256, 0, stream>>>(xb, wtin + wofs, bin + l * D_,
        tbuf, tbf, nullptr, nullptr, zpad, M_, D_, D_);
    // TreeFFN iter 0
    gemm2_k<1,2,64><<<g64, 256, 0, stream>>>(tbf, wtedge + (size_t)l * 2 * D_ * D_,
        bedge + l * D_, nullptr, msgb, nullptr, nullptr, zpad, M_, D_, 2 * D_);
    gemm2_k<2,3,64><<<g64, 256, 0, stream>>>(msgb, wtgate + wofs, bgate + l * D_,
        tbuf, tbf, msgb, nullptr, zpad, M_, D_, D_);
    // TreeFFN iter 1 + fused residual h += t
    gemm2_k<1,2,64><<<g64, 256, 0, stream>>>(tbf, wtedge + (size_t)l * 2 * D_ * D_,
        bedge + l * D_, nullptr, msgb, nullptr, nullptr, zpad, M_, D_, 2 * D_);
    gemm2_k<2,5,64><<<g64, 256, 0, stream>>>(msgb, wtgate + wofs, bgate + l * D_,
        tbuf, nullptr, msgb, hbuf, zpad, M_, D_, D_);
  }
  ln_k<<<M_, 256, 0, stream>>>(hbuf, lnfw, lnfb, xb);
  gemm2_k<0,0,128><<<dim3(V_ / 128, M_ / 128), 256, 0, stream>>>(xb, wthead, nullptr,
      out, nullptr, nullptr, nullptr, zpad, M_, V_, D_);
}

// Round 4
// 1358.926 us; speedup vs baseline: 4.7239x; 1.0347x over previous
//
#include <hip/hip_runtime.h>
#include <hip/hip_bf16.h>
#include <stdint.h>

#define V_ 32000
#define D_ 512
#define H_ 8
#define L_ 6
#define S_ 1024
#define B_ 4
#define DH_ 64
#define M_ (B_*S_)   // 4096

typedef __attribute__((ext_vector_type(8))) short bf16x8;
typedef __attribute__((ext_vector_type(4))) float f32x4;

__device__ __forceinline__ short f2bs(float f) {
  union { float f; uint32_t u; } x; x.f = f;
  uint32_t r = (x.u + 0x7FFFu + ((x.u >> 16) & 1u)) >> 16;
  return (short)r;
}
__device__ __forceinline__ float bs2f(short s) {
  union { uint32_t u; float f; } x; x.u = ((uint32_t)(uint16_t)s) << 16;
  return x.f;
}

__device__ __forceinline__ f32x4 mfma16(bf16x8 a, bf16x8 b, f32x4 c) {
  return __builtin_amdgcn_mfma_f32_16x16x32_bf16(a, b, c, 0, 0, 0);
}

// async global->LDS, 16B per lane; LDS dest = wave-uniform base + lane*16
__device__ __forceinline__ void gload16(const short* g, char* lds) {
  __builtin_amdgcn_global_load_lds(
      (const __attribute__((address_space(1))) uint32_t*)g,
      (__attribute__((address_space(3))) uint32_t*)lds, 16, 0, 0);
}

// ---- transpose + fp32->bf16 convert: out[(orow0+n)*K + k] = in[k*N+n] ----
__global__ __launch_bounds__(256) void transpose_cvt(const float* __restrict__ in,
    short* __restrict__ out, int K, int N, size_t in_slab, size_t out_slab, int orow0) {
  __shared__ float tile[32][33];
  const float* inp = in + (size_t)blockIdx.z * in_slab;
  short* outp = out + (size_t)blockIdx.z * out_slab;
  int kb = blockIdx.y * 32, nb = blockIdx.x * 32;
  int tx = threadIdx.x, ty = threadIdx.y;   // block (32,8)
  for (int r = ty; r < 32; r += 8) {
    int k = kb + r, n = nb + tx;
    tile[r][tx] = (k < K && n < N) ? inp[(size_t)k * N + n] : 0.f;
  }
  __syncthreads();
  for (int r = ty; r < 32; r += 8) {
    int n = nb + r, k = kb + tx;
    if (n < N && k < K) outp[(size_t)(orow0 + n) * K + k] = f2bs(tile[tx][r]);
  }
}

__global__ __launch_bounds__(256) void pack_qkv_bias(const float* __restrict__ bq,
    const float* __restrict__ bk, const float* __restrict__ bv, float* __restrict__ o) {
  int i = blockIdx.x * 256 + threadIdx.x;   // < L_*1536
  int l = i / 1536, c = i - l * 1536;
  float v = (c < 512) ? bq[l * 512 + c] : (c < 1024) ? bk[l * 512 + c - 512]
                                                     : bv[l * 512 + c - 1024];
  o[i] = v;
}

// ---- embedding ----
__global__ __launch_bounds__(256) void embed_k(const int* __restrict__ ids,
    const float* __restrict__ tok, const float* __restrict__ pos, float* __restrict__ h) {
  int bs = blockIdx.x;
  int tid = threadIdx.x;
  int s = bs & (S_ - 1);
  int id = ids[bs];
  float2 te = *(const float2*)(tok + (size_t)id * D_ + tid * 2);
  float2 pe = *(const float2*)(pos + (size_t)s * D_ + tid * 2);
  float2 r; r.x = te.x + pe.x; r.y = te.y + pe.y;
  *(float2*)(h + (size_t)bs * D_ + tid * 2) = r;
}

// ---- LayerNorm -> bf16 ----
__global__ __launch_bounds__(256) void ln_k(const float* __restrict__ in,
    const float* __restrict__ w, const float* __restrict__ bb, short* __restrict__ outb) {
  int row = blockIdx.x, tid = threadIdx.x;
  int lane = tid & 63, wv = tid >> 6;
  const float* x = in + (size_t)row * D_;
  float2 v = *(const float2*)(x + tid * 2);
  float s = v.x + v.y;
  #pragma unroll
  for (int o = 32; o; o >>= 1) s += __shfl_xor(s, o);
  __shared__ float red[8];
  if (lane == 0) red[wv] = s;
  __syncthreads();
  float mu = (red[0] + red[1] + red[2] + red[3]) * (1.f / D_);
  float dx = v.x - mu, dy = v.y - mu;
  float s2 = dx * dx + dy * dy;
  #pragma unroll
  for (int o = 32; o; o >>= 1) s2 += __shfl_xor(s2, o);
  if (lane == 0) red[4 + wv] = s2;
  __syncthreads();
  float var = (red[4] + red[5] + red[6] + red[7]) * (1.f / D_);
  float rs = rsqrtf(var + 1e-5f);
  int c = tid * 2;
  float y0 = dx * rs * w[c] + bb[c];
  float y1 = dy * rs * w[c + 1] + bb[c + 1];
  short* o2 = outb + (size_t)row * D_ + c;
  o2[0] = f2bs(y0); o2[1] = f2bs(y1);
}

// ========== 128xBN MFMA GEMM, BK=64, double-buffered 2-phase pipeline ==========
// grid: (M/128, N/BN), blockIdx.x = m-tile (fastest -> consecutive blocks share B).
// LDS row stride 128B; element (row,kel) stored at byte row*128 + (kel*2 ^ ((row&7)<<4))
// via pre-swizzled GLOBAL source (rule 21), read back with the same XOR.
// AMODE: 0 plain; 1 concat(t[m],t[m+1]); 2 shifted (A[m]=msg[m-1]).
// EMODE: 0 Cf=acc+b (+Cb if nonnull; nontemporal Cf if Cb null); 1 Cf+=; 2 Cb=relu;
//        3 gate-iter0; 5 gate-iter1 fused residual; 4 QKV bf16 (q cols scaled).
template<int AMODE, int EMODE, int BN>
__global__ __launch_bounds__(256) void gemm2_k(
    const short* __restrict__ A, const short* __restrict__ Wt,
    const float* __restrict__ bias, float* __restrict__ Cf,
    short* __restrict__ Cb, const short* __restrict__ Agg,
    float* __restrict__ Hf, const short* __restrict__ zpad,
    int M, int N, int K)
{
  constexpr int NF = BN / 32;              // B-frags per wave (2 or 4)
  constexpr int BR = BN / 32;              // B staging rounds (32 rows each)
  __shared__ __align__(16) char As[2][128 * 128];
  __shared__ __align__(16) char Bs[2][BN * 128];
  const int tid = threadIdx.x;
  const int lane = tid & 63, w = tid >> 6;
  const int m0 = blockIdx.x * 128, n0 = blockIdx.y * BN;
  const int l15 = lane & 15, l4 = lane >> 4;
  const int wm = (w >> 1) * 64, wn = (w & 1) * (BN / 2);

  // ---- staging source addresses (pre-swizzled globals); round r covers 32 rows ----
  const int lrow_b = tid >> 3;                     // 0..31
  const int kel0 = (tid & 7) * 8;
  const short* agp[4];
  const short* agpHi[4];
  #pragma unroll
  for (int r = 0; r < 4; ++r) {
    int lrow = r * 32 + lrow_b;
    int row = m0 + lrow;
    int kel = kel0 ^ ((lrow & 7) << 3);
    if (AMODE == 0) {
      agp[r] = A + (size_t)row * K + kel;
    } else if (AMODE == 1) {
      agp[r]   = A + (size_t)row * D_ + kel;
      agpHi[r] = ((row & (S_ - 1)) == (S_ - 1)) ? zpad + kel
                                                : A + (size_t)(row + 1) * D_ + kel;
    } else {
      agp[r] = ((row & (S_ - 1)) == 0) ? zpad + kel : A + (size_t)(row - 1) * D_ + kel;
    }
  }
  const short* bgp[BR];
  #pragma unroll
  for (int r = 0; r < BR; ++r) {
    int lrow = r * 32 + lrow_b;
    int kel = kel0 ^ ((lrow & 7) << 3);
    bgp[r] = Wt + (size_t)(n0 + lrow) * K + kel;
  }

  auto stage = [&](int buf, int k0) {
    #pragma unroll
    for (int r = 0; r < 4; ++r) {
      const short* gp;
      if (AMODE == 1) gp = (k0 < D_) ? agp[r] + k0 : agpHi[r] + (k0 - D_);
      else gp = agp[r] + k0;
      gload16(gp, As[buf] + r * 4096 + w * 1024);
    }
    #pragma unroll
    for (int r = 0; r < BR; ++r)
      gload16(bgp[r] + k0, Bs[buf] + r * 4096 + w * 1024);
  };

  // ---- fragment read offsets ----
  const int rswz = (l15 & 7) << 4;                 // byte XOR within 128B row
  int aoff[4], boff[NF];
  #pragma unroll
  for (int i = 0; i < 4; ++i) aoff[i] = (wm + i * 16 + l15) * 128;
  #pragma unroll
  for (int j = 0; j < NF; ++j) boff[j] = (wn + j * 16 + l15) * 128;

  f32x4 acc[4][NF] = {};

  const int nk = K >> 6;
  stage(0, 0);
  asm volatile("s_waitcnt vmcnt(0)" ::: "memory");
  __syncthreads();
  int cur = 0;
  for (int t = 0; t < nk; ++t) {
    if (t + 1 < nk) stage(cur ^ 1, (t + 1) * 64);
    #pragma unroll
    for (int kk = 0; kk < 2; ++kk) {
      const int cb = ((kk * 64 + l4 * 16)) ^ rswz;
      bf16x8 af[4], bfr[NF];
      #pragma unroll
      for (int i = 0; i < 4; ++i) af[i] = *(const bf16x8*)(As[cur] + aoff[i] + cb);
      #pragma unroll
      for (int j = 0; j < NF; ++j) bfr[j] = *(const bf16x8*)(Bs[cur] + boff[j] + cb);
      #pragma unroll
      for (int i = 0; i < 4; ++i)
        #pragma unroll
        for (int j = 0; j < NF; ++j)
          acc[i][j] = mfma16(af[i], bfr[j], acc[i][j]);
    }
    asm volatile("s_waitcnt vmcnt(0)" ::: "memory");
    __syncthreads();
    cur ^= 1;
  }

  const int rowb = m0 + wm + l4 * 4;
  const int colb = n0 + wn + l15;
  #pragma unroll
  for (int i = 0; i < 4; ++i) {
    #pragma unroll
    for (int j = 0; j < NF; ++j) {
      int col = colb + j * 16;
      float bias_v = bias ? bias[col] : 0.f;
      #pragma unroll
      for (int r = 0; r < 4; ++r) {
        int row = rowb + i * 16 + r;
        size_t idx = (size_t)row * N + col;
        float v = acc[i][j][r] + bias_v;
        if (EMODE == 0) {
          if (Cb) { Cf[idx] = v; Cb[idx] = f2bs(v); }
          else __builtin_nontemporal_store(v, &Cf[idx]);
        } else if (EMODE == 1) {
          Cf[idx] += v;
        } else if (EMODE == 2) {
          Cb[idx] = f2bs(fmaxf(v, 0.f));
        } else if (EMODE == 3) {
          float g = 1.f / (1.f + __expf(-v));
          float aggv = ((row & (S_ - 1)) == 0) ? 0.f : bs2f(Agg[idx - N]);
          float tn = Cf[idx] + g * aggv;
          Cf[idx] = tn; Cb[idx] = f2bs(tn);
        } else if (EMODE == 5) {
          float g = 1.f / (1.f + __expf(-v));
          float aggv = ((row & (S_ - 1)) == 0) ? 0.f : bs2f(Agg[idx - N]);
          Hf[idx] += Cf[idx] + g * aggv;
        } else {   // 4: QKV packed bf16; q cols pre-scaled into exp2 domain
          float sc = (col < D_) ? 0.180336880f : 1.f;   // 0.125 * log2(e)
          Cb[idx] = f2bs(v * sc);
        }
      }
    }
  }
}

// ---- flash attention on packed QKV [M][3*D_] bf16; Q pre-scaled (exp2 domain) ----
__global__ __launch_bounds__(256) void fattn_k(const short* __restrict__ Qkv,
    short* __restrict__ avb)
{
  __shared__ short Ks[64][72];
  __shared__ short Vt[64][72];
  __shared__ short Ps[4][16][72];
  const int QS = 3 * D_;
  int tid = threadIdx.x, lane = tid & 63, w = tid >> 6;
  int bx = blockIdx.x;
  int qt = 15 - (bx >> 5);            // heavy tiles first
  int bh = bx & 31, b = bh >> 3, hh = bh & 7;
  int l15 = lane & 15, g = lane >> 4;

  int qrow = qt * 64 + w * 16 + l15;
  const short* qptr = Qkv + (size_t)(b * S_ + qrow) * QS + hh * DH_;
  uint4 qa0 = *(const uint4*)(qptr + g * 8);
  uint4 qa1 = *(const uint4*)(qptr + 32 + g * 8);

  f32x4 o[4] = {};
  float mrow[4], lrow[4];
  #pragma unroll
  for (int r = 0; r < 4; ++r) { mrow[r] = -1e30f; lrow[r] = 0.f; }

  // per-thread K/V staging addresses (two chunks of 8 elems)
  const int skey = tid >> 3;                      // +32 on chunk 1? no: c=tid+i*256
  (void)skey;
  auto gbase = [&](int kt, int i) {
    int c = tid + i * 256;
    int key = c >> 3, d0 = (c & 7) * 8;
    return Qkv + (size_t)(b * S_ + kt * 64 + key) * QS + hh * DH_ + d0;
  };
  uint4 kvA[2], vvA[2], kvB[2], vvB[2];
  auto load_t = [&](int kt, uint4 kv[2], uint4 vv[2]) {
    #pragma unroll
    for (int i = 0; i < 2; ++i) {
      const short* base = gbase(kt, i);
      kv[i] = *(const uint4*)(base + D_);
      vv[i] = *(const uint4*)(base + 2 * D_);
    }
  };
  auto store_t = [&](uint4 kv[2], uint4 vv[2]) {
    #pragma unroll
    for (int i = 0; i < 2; ++i) {
      int c = tid + i * 256;
      int key = c >> 3, d0 = (c & 7) * 8;
      *(uint4*)&Ks[key][d0] = kv[i];
      short vs[8]; *(uint4*)vs = vv[i];
      int a = (c & 7);
      #pragma unroll
      for (int j = 0; j < 8; ++j)
        Vt[d0 + j][key ^ (a << 3)] = vs[j];
    }
  };

  auto compute = [&](int kt) {
    int key0 = kt * 64;
    bool diag = (kt == qt);
    f32x4 sc[4] = {};
    #pragma unroll
    for (int f = 0; f < 4; ++f) {
      bf16x8 kb0 = *(const bf16x8*)&Ks[f * 16 + l15][g * 8];
      bf16x8 kb1 = *(const bf16x8*)&Ks[f * 16 + l15][32 + g * 8];
      sc[f] = mfma16(*(const bf16x8*)&qa0, kb0, sc[f]);
      sc[f] = mfma16(*(const bf16x8*)&qa1, kb1, sc[f]);
    }
    float p[4][4];
    #pragma unroll
    for (int r = 0; r < 4; ++r) {
      float s0[4];
      #pragma unroll
      for (int f = 0; f < 4; ++f) s0[f] = sc[f][r];
      if (diag) {
        int rowg = qt * 64 + w * 16 + g * 4 + r;
        #pragma unroll
        for (int f = 0; f < 4; ++f) {
          int keyg = key0 + f * 16 + l15;
          if (keyg > rowg) s0[f] = -1e30f;
        }
      }
      float cm = fmaxf(fmaxf(s0[0], s0[1]), fmaxf(s0[2], s0[3]));
      #pragma unroll
      for (int ofs = 1; ofs < 16; ofs <<= 1) cm = fmaxf(cm, __shfl_xor(cm, ofs));
      float mn = fmaxf(mrow[r], cm);
      float fr = exp2f(mrow[r] - mn);
      mrow[r] = mn;
      float ss = 0.f;
      #pragma unroll
      for (int f = 0; f < 4; ++f) { float e = exp2f(s0[f] - mn); p[f][r] = e; ss += e; }
      #pragma unroll
      for (int ofs = 1; ofs < 16; ofs <<= 1) ss += __shfl_xor(ss, ofs);
      lrow[r] = lrow[r] * fr + ss;
      #pragma unroll
      for (int nt = 0; nt < 4; ++nt) o[nt][r] *= fr;
    }
    #pragma unroll
    for (int f = 0; f < 4; ++f)
      #pragma unroll
      for (int r = 0; r < 4; ++r)
        Ps[w][g * 4 + r][f * 16 + l15] = f2bs(p[f][r]);
    bf16x8 pa0 = *(const bf16x8*)&Ps[w][l15][g * 8];
    bf16x8 pa1 = *(const bf16x8*)&Ps[w][l15][32 + g * 8];
    #pragma unroll
    for (int nt = 0; nt < 4; ++nt) {
      int dim = nt * 16 + l15;
      int vswz = ((dim >> 3) & 7) << 3;
      bf16x8 vb0 = *(const bf16x8*)&Vt[dim][(g * 8) ^ vswz];
      bf16x8 vb1 = *(const bf16x8*)&Vt[dim][(32 + g * 8) ^ vswz];
      o[nt] = mfma16(pa0, vb0, o[nt]);
      o[nt] = mfma16(pa1, vb1, o[nt]);
    }
  };

  int ntiles = qt + 1;
  load_t(0, kvA, vvA);
  int kt = 0;
  while (true) {
    __syncthreads();
    store_t(kvA, vvA);
    if (kt + 1 < ntiles) load_t(kt + 1, kvB, vvB);
    __syncthreads();
    compute(kt);
    ++kt; if (kt >= ntiles) break;
    __syncthreads();
    store_t(kvB, vvB);
    if (kt + 1 < ntiles) load_t(kt + 1, kvA, vvA);
    __syncthreads();
    compute(kt);
    ++kt; if (kt >= ntiles) break;
  }

  #pragma unroll
  for (int r = 0; r < 4; ++r) {
    float inv = 1.f / lrow[r];
    int rowg = qt * 64 + w * 16 + g * 4 + r;
    short* op = avb + (size_t)(b * S_ + rowg) * D_ + hh * DH_;
    #pragma unroll
    for (int nt = 0; nt < 4; ++nt)
      op[nt * 16 + l15] = f2bs(o[nt][r] * inv);
  }
}

extern "C" void kernel_launch(void* const* d_in, const int* in_sizes, int n_in,
                              void* d_out, int out_size, void* d_ws, size_t ws_size,
                              hipStream_t stream) {
  const int*   ids   = (const int*)d_in[0];
  const float* tok   = (const float*)d_in[1];
  const float* pos   = (const float*)d_in[2];
  const float* Wq    = (const float*)d_in[3];
  const float* bq    = (const float*)d_in[4];
  const float* Wk    = (const float*)d_in[5];
  const float* bk    = (const float*)d_in[6];
  const float* Wv    = (const float*)d_in[7];
  const float* bv    = (const float*)d_in[8];
  const float* Wo    = (const float*)d_in[9];
  const float* bo    = (const float*)d_in[10];
  const float* ln1w  = (const float*)d_in[11];
  const float* ln1b  = (const float*)d_in[12];
  const float* ln2w  = (const float*)d_in[13];
  const float* ln2b  = (const float*)d_in[14];
  const float* Win   = (const float*)d_in[15];
  const float* bin   = (const float*)d_in[16];
  const float* Wedge = (const float*)d_in[17];
  const float* bedge = (const float*)d_in[18];
  const float* Wgate = (const float*)d_in[19];
  const float* bgate = (const float*)d_in[20];
  const float* lnfw  = (const float*)d_in[21];
  const float* lnfb  = (const float*)d_in[22];
  const float* Whead = (const float*)d_in[23];
  float* out = (float*)d_out;

  char* ws = (char*)d_ws;
  size_t off = 0;
  auto alloc = [&](size_t bytes) {
    void* p = ws + off;
    off = (off + bytes + 255) & ~(size_t)255;
    return p;
  };
  short* wqkv   = (short*)alloc((size_t)L_ * 3 * D_ * D_ * 2);
  float* bqkv   = (float*)alloc((size_t)L_ * 3 * D_ * 4);
  short* wto    = (short*)alloc((size_t)L_ * D_ * D_ * 2);
  short* wtin   = (short*)alloc((size_t)L_ * D_ * D_ * 2);
  short* wtgate = (short*)alloc((size_t)L_ * D_ * D_ * 2);
  short* wtedge = (short*)alloc((size_t)L_ * 2 * D_ * D_ * 2);
  short* wthead = (short*)alloc((size_t)V_ * D_ * 2);
  short* zpad   = (short*)alloc(4096);
  float* hbuf   = (float*)alloc((size_t)M_ * D_ * 4);
  short* xb     = (short*)alloc((size_t)M_ * D_ * 2);
  short* qkvb   = (short*)alloc((size_t)M_ * 3 * D_ * 2);
  short* avb    = (short*)alloc((size_t)M_ * D_ * 2);
  float* tbuf   = (float*)alloc((size_t)M_ * D_ * 4);
  short* tbf    = (short*)alloc((size_t)M_ * D_ * 2);
  short* msgb   = (short*)alloc((size_t)M_ * D_ * 2);
  (void)ws_size; (void)in_sizes; (void)n_in; (void)out_size;

  hipMemsetAsync(zpad, 0, 4096, stream);

  dim3 tblk(32, 8);
  transpose_cvt<<<dim3(16, 16, L_), tblk, 0, stream>>>(Wq, wqkv, D_, D_, (size_t)D_*D_, (size_t)3*D_*D_, 0);
  transpose_cvt<<<dim3(16, 16, L_), tblk, 0, stream>>>(Wk, wqkv, D_, D_, (size_t)D_*D_, (size_t)3*D_*D_, D_);
  transpose_cvt<<<dim3(16, 16, L_), tblk, 0, stream>>>(Wv, wqkv, D_, D_, (size_t)D_*D_, (size_t)3*D_*D_, 2*D_);
  transpose_cvt<<<dim3(16, 16, L_), tblk, 0, stream>>>(Wo, wto, D_, D_, (size_t)D_*D_, (size_t)D_*D_, 0);
  transpose_cvt<<<dim3(16, 16, L_), tblk, 0, stream>>>(Win, wtin, D_, D_, (size_t)D_*D_, (size_t)D_*D_, 0);
  transpose_cvt<<<dim3(16, 16, L_), tblk, 0, stream>>>(Wgate, wtgate, D_, D_, (size_t)D_*D_, (size_t)D_*D_, 0);
  transpose_cvt<<<dim3(16, 32, L_), tblk, 0, stream>>>(Wedge, wtedge, 2*D_, D_, (size_t)2*D_*D_, (size_t)2*D_*D_, 0);
  transpose_cvt<<<dim3(V_/32, 16, 1), tblk, 0, stream>>>(Whead, wthead, D_, V_, (size_t)D_*V_, (size_t)D_*V_, 0);
  pack_qkv_bias<<<(L_ * 3 * D_) / 256, 256, 0, stream>>>(bq, bk, bv, bqkv);

  embed_k<<<M_, 256, 0, stream>>>(ids, tok, pos, hbuf);

  dim3 g64(M_ / 128, D_ / 64);        // (32,8), m-fastest
  dim3 gqkv(M_ / 128, 3 * D_ / 128);  // (32,12)
  for (int l = 0; l < L_; ++l) {
    size_t wofs = (size_t)l * D_ * D_;
    ln_k<<<M_, 256, 0, stream>>>(hbuf, ln1w + l * D_, ln1b + l * D_, xb);
    gemm2_k<0,4,128><<<gqkv, 256, 0, stream>>>(xb, wqkv + (size_t)l * 3 * D_ * D_,
        bqkv + (size_t)l * 3 * D_, nullptr, qkvb, nullptr, nullptr, zpad, M_, 3 * D_, D_);
    fattn_k<<<B_ * H_ * (S_ / 64), 256, 0, stream>>>(qkvb, avb);
    gemm2_k<0,1,64><<<g64, 256, 0, stream>>>(avb, wto + wofs, bo + l * D_,
        hbuf, nullptr, nullptr, nullptr, zpad, M_, D_, D_);
    ln_k<<<M_, 256, 0, stream>>>(hbuf, ln2w + l * D_, ln2b + l * D_, xb);
    gemm2_k<0,0,64><<<g64, 256, 0, stream>>>(xb, wtin + wofs, bin + l * D_,
        tbuf, tbf, nullptr, nullptr, zpad, M_, D_, D_);
    // TreeFFN iter 0
    gemm2_k<1,2,64><<<g64, 256, 0, stream>>>(tbf, wtedge + (size_t)l * 2 * D_ * D_,
        bedge + l * D_, nullptr, msgb, nullptr, nullptr, zpad, M_, D_, 2 * D_);
    gemm2_k<2,3,64><<<g64, 256, 0, stream>>>(msgb, wtgate + wofs, bgate + l * D_,
        tbuf, tbf, msgb, nullptr, zpad, M_, D_, D_);
    // TreeFFN iter 1 + fused residual h += t
    gemm2_k<1,2,64><<<g64, 256, 0, stream>>>(tbf, wtedge + (size_t)l * 2 * D_ * D_,
        bedge + l * D_, nullptr, msgb, nullptr, nullptr, zpad, M_, D_, 2 * D_);
    gemm2_k<2,5,64><<<g64, 256, 0, stream>>>(msgb, wtgate + wofs, bgate + l * D_,
        tbuf, nullptr, msgb, hbuf, zpad, M_, D_, D_);
  }
  ln_k<<<M_, 256, 0, stream>>>(hbuf, lnfw, lnfb, xb);
  gemm2_k<0,0,128><<<dim3(M_ / 128, V_ / 128), 256, 0, stream>>>(xb, wthead, nullptr,
      out, nullptr, nullptr, nullptr, zpad, M_, V_, D_);
}

// Round 5
// 1075.416 us; speedup vs baseline: 5.9693x; 1.2636x over previous
//
#include <hip/hip_runtime.h>
#include <hip/hip_bf16.h>
#include <stdint.h>

#define V_ 32000
#define D_ 512
#define H_ 8
#define L_ 6
#define S_ 1024
#define B_ 4
#define DH_ 64
#define M_ (B_*S_)   // 4096

typedef __attribute__((ext_vector_type(8))) short bf16x8;
typedef __attribute__((ext_vector_type(4))) float f32x4;

__device__ __forceinline__ short f2bs(float f) {
  union { float f; uint32_t u; } x; x.f = f;
  uint32_t r = (x.u + 0x7FFFu + ((x.u >> 16) & 1u)) >> 16;
  return (short)r;
}
__device__ __forceinline__ float bs2f(short s) {
  union { uint32_t u; float f; } x; x.u = ((uint32_t)(uint16_t)s) << 16;
  return x.f;
}

__device__ __forceinline__ f32x4 mfma16(bf16x8 a, bf16x8 b, f32x4 c) {
  return __builtin_amdgcn_mfma_f32_16x16x32_bf16(a, b, c, 0, 0, 0);
}

// async global->LDS, 16B per lane; LDS dest = wave-uniform base + lane*16
__device__ __forceinline__ void gload16(const short* g, char* lds) {
  __builtin_amdgcn_global_load_lds(
      (const __attribute__((address_space(1))) uint32_t*)g,
      (__attribute__((address_space(3))) uint32_t*)lds, 16, 0, 0);
}

template<int N> __device__ __forceinline__ void waitvm() {
  if constexpr (N == 0) asm volatile("s_waitcnt vmcnt(0)" ::: "memory");
  else if constexpr (N == 4) asm volatile("s_waitcnt vmcnt(4)" ::: "memory");
  else if constexpr (N == 6) asm volatile("s_waitcnt vmcnt(6)" ::: "memory");
  else if constexpr (N == 8) asm volatile("s_waitcnt vmcnt(8)" ::: "memory");
}

// ---- transpose + fp32->bf16 convert: out[(orow0+n)*K + k] = in[k*N+n] ----
__global__ __launch_bounds__(256) void transpose_cvt(const float* __restrict__ in,
    short* __restrict__ out, int K, int N, size_t in_slab, size_t out_slab, int orow0) {
  __shared__ float tile[32][33];
  const float* inp = in + (size_t)blockIdx.z * in_slab;
  short* outp = out + (size_t)blockIdx.z * out_slab;
  int kb = blockIdx.y * 32, nb = blockIdx.x * 32;
  int tx = threadIdx.x, ty = threadIdx.y;   // block (32,8)
  for (int r = ty; r < 32; r += 8) {
    int k = kb + r, n = nb + tx;
    tile[r][tx] = (k < K && n < N) ? inp[(size_t)k * N + n] : 0.f;
  }
  __syncthreads();
  for (int r = ty; r < 32; r += 8) {
    int n = nb + r, k = kb + tx;
    if (n < N && k < K) outp[(size_t)(orow0 + n) * K + k] = f2bs(tile[tx][r]);
  }
}

__global__ __launch_bounds__(256) void pack_qkv_bias(const float* __restrict__ bq,
    const float* __restrict__ bk, const float* __restrict__ bv, float* __restrict__ o) {
  int i = blockIdx.x * 256 + threadIdx.x;   // < L_*1536
  int l = i / 1536, c = i - l * 1536;
  float v = (c < 512) ? bq[l * 512 + c] : (c < 1024) ? bk[l * 512 + c - 512]
                                                     : bv[l * 512 + c - 1024];
  o[i] = v;
}

// ---- embedding ----
__global__ __launch_bounds__(256) void embed_k(const int* __restrict__ ids,
    const float* __restrict__ tok, const float* __restrict__ pos, float* __restrict__ h) {
  int bs = blockIdx.x;
  int tid = threadIdx.x;
  int s = bs & (S_ - 1);
  int id = ids[bs];
  float2 te = *(const float2*)(tok + (size_t)id * D_ + tid * 2);
  float2 pe = *(const float2*)(pos + (size_t)s * D_ + tid * 2);
  float2 r; r.x = te.x + pe.x; r.y = te.y + pe.y;
  *(float2*)(h + (size_t)bs * D_ + tid * 2) = r;
}

// ---- LayerNorm, one wave per row, 4 rows/block, no LDS ----
__global__ __launch_bounds__(256) void ln4_k(const float* __restrict__ in,
    const float* __restrict__ w, const float* __restrict__ bb, short* __restrict__ outb) {
  int wv = threadIdx.x >> 6, lane = threadIdx.x & 63;
  int row = blockIdx.x * 4 + wv;
  const float* x = in + (size_t)row * D_ + lane * 8;
  float4 v0 = *(const float4*)x;
  float4 v1 = *(const float4*)(x + 4);
  float s = v0.x + v0.y + v0.z + v0.w + v1.x + v1.y + v1.z + v1.w;
  #pragma unroll
  for (int o = 32; o; o >>= 1) s += __shfl_xor(s, o);
  float mu = s * (1.f / D_);
  float d[8] = {v0.x-mu, v0.y-mu, v0.z-mu, v0.w-mu, v1.x-mu, v1.y-mu, v1.z-mu, v1.w-mu};
  float s2 = 0.f;
  #pragma unroll
  for (int j = 0; j < 8; ++j) s2 += d[j] * d[j];
  #pragma unroll
  for (int o = 32; o; o >>= 1) s2 += __shfl_xor(s2, o);
  float rs = rsqrtf(s2 * (1.f / D_) + 1e-5f);
  float4 w0 = *(const float4*)(w + lane * 8);
  float4 w1 = *(const float4*)(w + lane * 8 + 4);
  float4 b0 = *(const float4*)(bb + lane * 8);
  float4 b1 = *(const float4*)(bb + lane * 8 + 4);
  float wj[8] = {w0.x,w0.y,w0.z,w0.w,w1.x,w1.y,w1.z,w1.w};
  float bj[8] = {b0.x,b0.y,b0.z,b0.w,b1.x,b1.y,b1.z,b1.w};
  short o8[8];
  #pragma unroll
  for (int j = 0; j < 8; ++j) o8[j] = f2bs(d[j] * rs * wj[j] + bj[j]);
  *(uint4*)(outb + (size_t)row * D_ + lane * 8) = *(uint4*)o8;
}

// ========== 64xBN MFMA GEMM, BK=64, dbuf + counted vmcnt ==========
// grid (M/64, N/BN), x = m-tile fastest. LDS row = 128 B, byte-XOR swizzle
// ((row&7)<<4) applied on pre-swizzled GLOBAL source + on ds_read (rule 21).
// AMODE: 0 plain; 1 concat(t[m],t[m+1]); 2 shifted (A[m]=msg[m-1]).
// EMODE: 0 Cf=acc+b (+Cb if nonnull, else nontemporal); 1 Cf+=; 2 Cb=relu;
//        3 gate-iter0 (t+=sig*agg); 5 gate-iter1 (Hf+=t+sig*agg); 4 QKV bf16.
template<int AMODE, int EMODE, int BN>
__global__ __launch_bounds__(256) void gemm3_k(
    const short* __restrict__ A, const short* __restrict__ Wt,
    const float* __restrict__ bias, float* __restrict__ Cf,
    short* __restrict__ Cb, const short* __restrict__ Agg,
    float* __restrict__ Hf, const short* __restrict__ zpad,
    int M, int N, int K)
{
  constexpr int NF = BN / 32;             // B frags per wave
  constexpr int BR = BN / 32;             // B staging rounds (32 rows each)
  constexpr int LOADS = 2 + BR;           // gload_lds per wave per stage
  __shared__ __align__(16) char As[2][64 * 128];
  __shared__ __align__(16) char Bs[2][BN * 128];
  const int tid = threadIdx.x;
  const int lane = tid & 63, w = tid >> 6;
  const int m0 = blockIdx.x * 64, n0 = blockIdx.y * BN;
  const int l15 = lane & 15, l4 = lane >> 4;
  const int wm = (w >> 1) * 32, wn = (w & 1) * (BN / 2);

  const int lrow_b = tid >> 3;            // 0..31
  const int kel0 = (tid & 7) * 8;
  const short* agp[2];
  const short* agpHi[2];
  #pragma unroll
  for (int r = 0; r < 2; ++r) {
    int lrow = r * 32 + lrow_b;
    int row = m0 + lrow;
    int kel = kel0 ^ ((lrow & 7) << 3);
    if (AMODE == 0) {
      agp[r] = A + (size_t)row * K + kel;
    } else if (AMODE == 1) {
      agp[r]   = A + (size_t)row * D_ + kel;
      agpHi[r] = ((row & (S_ - 1)) == (S_ - 1)) ? zpad + kel
                                                : A + (size_t)(row + 1) * D_ + kel;
    } else {
      agp[r] = ((row & (S_ - 1)) == 0) ? zpad + kel : A + (size_t)(row - 1) * D_ + kel;
    }
  }
  const short* bgp[BR];
  #pragma unroll
  for (int r = 0; r < BR; ++r) {
    int lrow = r * 32 + lrow_b;
    int kel = kel0 ^ ((lrow & 7) << 3);
    bgp[r] = Wt + (size_t)(n0 + lrow) * K + kel;
  }

  auto stage = [&](int buf, int k0) {
    #pragma unroll
    for (int r = 0; r < 2; ++r) {
      const short* gp;
      if (AMODE == 1) gp = (k0 < D_) ? agp[r] + k0 : agpHi[r] + (k0 - D_);
      else gp = agp[r] + k0;
      gload16(gp, As[buf] + r * 4096 + w * 1024);
    }
    #pragma unroll
    for (int r = 0; r < BR; ++r)
      gload16(bgp[r] + k0, Bs[buf] + r * 4096 + w * 1024);
  };

  const int rswz = (l15 & 7) << 4;
  int aoff[2], boff[NF];
  #pragma unroll
  for (int i = 0; i < 2; ++i) aoff[i] = (wm + i * 16 + l15) * 128;
  #pragma unroll
  for (int j = 0; j < NF; ++j) boff[j] = (wn + j * 16 + l15) * 128;

  f32x4 acc[2][NF] = {};

  const int nk = K >> 6;
  stage(0, 0);
  for (int t = 0; t < nk; ++t) {
    const int cur = t & 1;
    if (t + 1 < nk) { stage(cur ^ 1, (t + 1) * 64); waitvm<LOADS>(); }
    else waitvm<0>();
    __syncthreads();
    #pragma unroll
    for (int kk = 0; kk < 2; ++kk) {
      const int cb = (kk * 64 + l4 * 16) ^ rswz;
      bf16x8 af[2], bfr[NF];
      #pragma unroll
      for (int i = 0; i < 2; ++i) af[i] = *(const bf16x8*)(As[cur] + aoff[i] + cb);
      #pragma unroll
      for (int j = 0; j < NF; ++j) bfr[j] = *(const bf16x8*)(Bs[cur] + boff[j] + cb);
      __builtin_amdgcn_s_setprio(1);
      #pragma unroll
      for (int i = 0; i < 2; ++i)
        #pragma unroll
        for (int j = 0; j < NF; ++j)
          acc[i][j] = mfma16(af[i], bfr[j], acc[i][j]);
      __builtin_amdgcn_s_setprio(0);
    }
    __syncthreads();
  }

  const int rowb = m0 + wm + l4 * 4;
  const int colb = n0 + wn + l15;
  #pragma unroll
  for (int i = 0; i < 2; ++i) {
    #pragma unroll
    for (int j = 0; j < NF; ++j) {
      int col = colb + j * 16;
      float bias_v = bias ? bias[col] : 0.f;
      #pragma unroll
      for (int r = 0; r < 4; ++r) {
        int row = rowb + i * 16 + r;
        size_t idx = (size_t)row * N + col;
        float v = acc[i][j][r] + bias_v;
        if (EMODE == 0) {
          if (Cb) { Cf[idx] = v; Cb[idx] = f2bs(v); }
          else __builtin_nontemporal_store(v, &Cf[idx]);
        } else if (EMODE == 1) {
          Cf[idx] += v;
        } else if (EMODE == 2) {
          Cb[idx] = f2bs(fmaxf(v, 0.f));
        } else if (EMODE == 3) {
          float g = 1.f / (1.f + __expf(-v));
          float aggv = ((row & (S_ - 1)) == 0) ? 0.f : bs2f(Agg[idx - N]);
          float tn = Cf[idx] + g * aggv;
          Cf[idx] = tn; Cb[idx] = f2bs(tn);
        } else if (EMODE == 5) {
          float g = 1.f / (1.f + __expf(-v));
          float aggv = ((row & (S_ - 1)) == 0) ? 0.f : bs2f(Agg[idx - N]);
          Hf[idx] += Cf[idx] + g * aggv;
        } else {   // 4: QKV packed bf16; q cols scaled into exp2 domain
          float sc = (col < D_) ? 0.180336880f : 1.f;   // 0.125 * log2(e)
          Cb[idx] = f2bs(v * sc);
        }
      }
    }
  }
}

// ========== 128x128 MFMA GEMM (head), BK=64, dbuf + counted vmcnt ==========
__global__ __launch_bounds__(256) void gemm2_k(
    const short* __restrict__ A, const short* __restrict__ Wt,
    float* __restrict__ Cf, int M, int N, int K)
{
  __shared__ __align__(16) char As[2][128 * 128];
  __shared__ __align__(16) char Bs[2][128 * 128];
  const int tid = threadIdx.x;
  const int lane = tid & 63, w = tid >> 6;
  const int m0 = blockIdx.x * 128, n0 = blockIdx.y * 128;
  const int l15 = lane & 15, l4 = lane >> 4;
  const int wm = (w >> 1) * 64, wn = (w & 1) * 64;

  const int lrow_b = tid >> 3;
  const int kel0 = (tid & 7) * 8;
  const short* agp[4];
  const short* bgp[4];
  #pragma unroll
  for (int r = 0; r < 4; ++r) {
    int lrow = r * 32 + lrow_b;
    int kel = kel0 ^ ((lrow & 7) << 3);
    agp[r] = A + (size_t)(m0 + lrow) * K + kel;
    bgp[r] = Wt + (size_t)(n0 + lrow) * K + kel;
  }
  auto stage = [&](int buf, int k0) {
    #pragma unroll
    for (int r = 0; r < 4; ++r) gload16(agp[r] + k0, As[buf] + r * 4096 + w * 1024);
    #pragma unroll
    for (int r = 0; r < 4; ++r) gload16(bgp[r] + k0, Bs[buf] + r * 4096 + w * 1024);
  };

  const int rswz = (l15 & 7) << 4;
  int aoff[4], boff[4];
  #pragma unroll
  for (int i = 0; i < 4; ++i) aoff[i] = (wm + i * 16 + l15) * 128;
  #pragma unroll
  for (int j = 0; j < 4; ++j) boff[j] = (wn + j * 16 + l15) * 128;

  f32x4 acc[4][4] = {};
  const int nk = K >> 6;
  stage(0, 0);
  for (int t = 0; t < nk; ++t) {
    const int cur = t & 1;
    if (t + 1 < nk) { stage(cur ^ 1, (t + 1) * 64); waitvm<8>(); }
    else waitvm<0>();
    __syncthreads();
    #pragma unroll
    for (int kk = 0; kk < 2; ++kk) {
      const int cb = (kk * 64 + l4 * 16) ^ rswz;
      bf16x8 af[4], bfr[4];
      #pragma unroll
      for (int i = 0; i < 4; ++i) af[i] = *(const bf16x8*)(As[cur] + aoff[i] + cb);
      #pragma unroll
      for (int j = 0; j < 4; ++j) bfr[j] = *(const bf16x8*)(Bs[cur] + boff[j] + cb);
      __builtin_amdgcn_s_setprio(1);
      #pragma unroll
      for (int i = 0; i < 4; ++i)
        #pragma unroll
        for (int j = 0; j < 4; ++j)
          acc[i][j] = mfma16(af[i], bfr[j], acc[i][j]);
      __builtin_amdgcn_s_setprio(0);
    }
    __syncthreads();
  }

  const int rowb = m0 + wm + l4 * 4;
  const int colb = n0 + wn + l15;
  #pragma unroll
  for (int i = 0; i < 4; ++i)
    #pragma unroll
    for (int j = 0; j < 4; ++j)
      #pragma unroll
      for (int r = 0; r < 4; ++r) {
        size_t idx = (size_t)(rowb + i * 16 + r) * N + colb + j * 16;
        __builtin_nontemporal_store(acc[i][j][r], &Cf[idx]);
      }
}

// ---- flash attention on packed QKV [M][3*D_] bf16; Q pre-scaled (exp2 domain) ----
__global__ __launch_bounds__(256) void fattn_k(const short* __restrict__ Qkv,
    short* __restrict__ avb)
{
  __shared__ short Ks[64][72];
  __shared__ short Vt[64][72];
  __shared__ short Ps[4][16][72];
  const int QS = 3 * D_;
  int tid = threadIdx.x, lane = tid & 63, w = tid >> 6;
  int bx = blockIdx.x;
  int qt = 15 - (bx >> 5);            // heavy tiles first
  int bh = bx & 31, b = bh >> 3, hh = bh & 7;
  int l15 = lane & 15, g = lane >> 4;

  int qrow = qt * 64 + w * 16 + l15;
  const short* qptr = Qkv + (size_t)(b * S_ + qrow) * QS + hh * DH_;
  uint4 qa0 = *(const uint4*)(qptr + g * 8);
  uint4 qa1 = *(const uint4*)(qptr + 32 + g * 8);

  f32x4 o[4] = {};
  float mrow[4], lrow[4];
  #pragma unroll
  for (int r = 0; r < 4; ++r) { mrow[r] = -1e30f; lrow[r] = 0.f; }

  auto gbase = [&](int kt, int i) {
    int c = tid + i * 256;
    int key = c >> 3, d0 = (c & 7) * 8;
    return Qkv + (size_t)(b * S_ + kt * 64 + key) * QS + hh * DH_ + d0;
  };
  uint4 kvA[2], vvA[2], kvB[2], vvB[2];
  auto load_t = [&](int kt, uint4 kv[2], uint4 vv[2]) {
    #pragma unroll
    for (int i = 0; i < 2; ++i) {
      const short* base = gbase(kt, i);
      kv[i] = *(const uint4*)(base + D_);
      vv[i] = *(const uint4*)(base + 2 * D_);
    }
  };
  auto store_t = [&](uint4 kv[2], uint4 vv[2]) {
    #pragma unroll
    for (int i = 0; i < 2; ++i) {
      int c = tid + i * 256;
      int key = c >> 3, d0 = (c & 7) * 8;
      *(uint4*)&Ks[key][d0] = kv[i];
      short vs[8]; *(uint4*)vs = vv[i];
      int a = (c & 7);
      #pragma unroll
      for (int j = 0; j < 8; ++j)
        Vt[d0 + j][key ^ (a << 3)] = vs[j];
    }
  };

  auto compute = [&](int kt) {
    int key0 = kt * 64;
    bool diag = (kt == qt);
    f32x4 sc[4] = {};
    __builtin_amdgcn_s_setprio(1);
    #pragma unroll
    for (int f = 0; f < 4; ++f) {
      bf16x8 kb0 = *(const bf16x8*)&Ks[f * 16 + l15][g * 8];
      bf16x8 kb1 = *(const bf16x8*)&Ks[f * 16 + l15][32 + g * 8];
      sc[f] = mfma16(*(const bf16x8*)&qa0, kb0, sc[f]);
      sc[f] = mfma16(*(const bf16x8*)&qa1, kb1, sc[f]);
    }
    __builtin_amdgcn_s_setprio(0);
    float p[4][4];
    #pragma unroll
    for (int r = 0; r < 4; ++r) {
      float s0[4];
      #pragma unroll
      for (int f = 0; f < 4; ++f) s0[f] = sc[f][r];
      if (diag) {
        int rowg = qt * 64 + w * 16 + g * 4 + r;
        #pragma unroll
        for (int f = 0; f < 4; ++f) {
          int keyg = key0 + f * 16 + l15;
          if (keyg > rowg) s0[f] = -1e30f;
        }
      }
      float cm = fmaxf(fmaxf(s0[0], s0[1]), fmaxf(s0[2], s0[3]));
      #pragma unroll
      for (int ofs = 1; ofs < 16; ofs <<= 1) cm = fmaxf(cm, __shfl_xor(cm, ofs));
      float mn = fmaxf(mrow[r], cm);
      float fr = exp2f(mrow[r] - mn);
      mrow[r] = mn;
      float ss = 0.f;
      #pragma unroll
      for (int f = 0; f < 4; ++f) { float e = exp2f(s0[f] - mn); p[f][r] = e; ss += e; }
      #pragma unroll
      for (int ofs = 1; ofs < 16; ofs <<= 1) ss += __shfl_xor(ss, ofs);
      lrow[r] = lrow[r] * fr + ss;
      #pragma unroll
      for (int nt = 0; nt < 4; ++nt) o[nt][r] *= fr;
    }
    #pragma unroll
    for (int f = 0; f < 4; ++f)
      #pragma unroll
      for (int r = 0; r < 4; ++r)
        Ps[w][g * 4 + r][f * 16 + l15] = f2bs(p[f][r]);
    bf16x8 pa0 = *(const bf16x8*)&Ps[w][l15][g * 8];
    bf16x8 pa1 = *(const bf16x8*)&Ps[w][l15][32 + g * 8];
    __builtin_amdgcn_s_setprio(1);
    #pragma unroll
    for (int nt = 0; nt < 4; ++nt) {
      int dim = nt * 16 + l15;
      int vswz = ((dim >> 3) & 7) << 3;
      bf16x8 vb0 = *(const bf16x8*)&Vt[dim][(g * 8) ^ vswz];
      bf16x8 vb1 = *(const bf16x8*)&Vt[dim][(32 + g * 8) ^ vswz];
      o[nt] = mfma16(pa0, vb0, o[nt]);
      o[nt] = mfma16(pa1, vb1, o[nt]);
    }
    __builtin_amdgcn_s_setprio(0);
  };

  int ntiles = qt + 1;
  load_t(0, kvA, vvA);
  int kt = 0;
  while (true) {
    __syncthreads();
    store_t(kvA, vvA);
    if (kt + 1 < ntiles) load_t(kt + 1, kvB, vvB);
    __syncthreads();
    compute(kt);
    ++kt; if (kt >= ntiles) break;
    __syncthreads();
    store_t(kvB, vvB);
    if (kt + 1 < ntiles) load_t(kt + 1, kvA, vvA);
    __syncthreads();
    compute(kt);
    ++kt; if (kt >= ntiles) break;
  }

  #pragma unroll
  for (int r = 0; r < 4; ++r) {
    float inv = 1.f / lrow[r];
    int rowg = qt * 64 + w * 16 + g * 4 + r;
    short* op = avb + (size_t)(b * S_ + rowg) * D_ + hh * DH_;
    #pragma unroll
    for (int nt = 0; nt < 4; ++nt)
      op[nt * 16 + l15] = f2bs(o[nt][r] * inv);
  }
}

extern "C" void kernel_launch(void* const* d_in, const int* in_sizes, int n_in,
                              void* d_out, int out_size, void* d_ws, size_t ws_size,
                              hipStream_t stream) {
  const int*   ids   = (const int*)d_in[0];
  const float* tok   = (const float*)d_in[1];
  const float* pos   = (const float*)d_in[2];
  const float* Wq    = (const float*)d_in[3];
  const float* bq    = (const float*)d_in[4];
  const float* Wk    = (const float*)d_in[5];
  const float* bk    = (const float*)d_in[6];
  const float* Wv    = (const float*)d_in[7];
  const float* bv    = (const float*)d_in[8];
  const float* Wo    = (const float*)d_in[9];
  const float* bo    = (const float*)d_in[10];
  const float* ln1w  = (const float*)d_in[11];
  const float* ln1b  = (const float*)d_in[12];
  const float* ln2w  = (const float*)d_in[13];
  const float* ln2b  = (const float*)d_in[14];
  const float* Win   = (const float*)d_in[15];
  const float* bin   = (const float*)d_in[16];
  const float* Wedge = (const float*)d_in[17];
  const float* bedge = (const float*)d_in[18];
  const float* Wgate = (const float*)d_in[19];
  const float* bgate = (const float*)d_in[20];
  const float* lnfw  = (const float*)d_in[21];
  const float* lnfb  = (const float*)d_in[22];
  const float* Whead = (const float*)d_in[23];
  float* out = (float*)d_out;

  char* ws = (char*)d_ws;
  size_t off = 0;
  auto alloc = [&](size_t bytes) {
    void* p = ws + off;
    off = (off + bytes + 255) & ~(size_t)255;
    return p;
  };
  short* wqkv   = (short*)alloc((size_t)L_ * 3 * D_ * D_ * 2);
  float* bqkv   = (float*)alloc((size_t)L_ * 3 * D_ * 4);
  short* wto    = (short*)alloc((size_t)L_ * D_ * D_ * 2);
  short* wtin   = (short*)alloc((size_t)L_ * D_ * D_ * 2);
  short* wtgate = (short*)alloc((size_t)L_ * D_ * D_ * 2);
  short* wtedge = (short*)alloc((size_t)L_ * 2 * D_ * D_ * 2);
  short* wthead = (short*)alloc((size_t)V_ * D_ * 2);
  short* zpad   = (short*)alloc(4096);
  float* hbuf   = (float*)alloc((size_t)M_ * D_ * 4);
  short* xb     = (short*)alloc((size_t)M_ * D_ * 2);
  short* qkvb   = (short*)alloc((size_t)M_ * 3 * D_ * 2);
  short* avb    = (short*)alloc((size_t)M_ * D_ * 2);
  float* tbuf   = (float*)alloc((size_t)M_ * D_ * 4);
  short* tbf    = (short*)alloc((size_t)M_ * D_ * 2);
  short* msgb   = (short*)alloc((size_t)M_ * D_ * 2);
  (void)ws_size; (void)in_sizes; (void)n_in; (void)out_size;

  hipMemsetAsync(zpad, 0, 4096, stream);

  dim3 tblk(32, 8);
  transpose_cvt<<<dim3(16, 16, L_), tblk, 0, stream>>>(Wq, wqkv, D_, D_, (size_t)D_*D_, (size_t)3*D_*D_, 0);
  transpose_cvt<<<dim3(16, 16, L_), tblk, 0, stream>>>(Wk, wqkv, D_, D_, (size_t)D_*D_, (size_t)3*D_*D_, D_);
  transpose_cvt<<<dim3(16, 16, L_), tblk, 0, stream>>>(Wv, wqkv, D_, D_, (size_t)D_*D_, (size_t)3*D_*D_, 2*D_);
  transpose_cvt<<<dim3(16, 16, L_), tblk, 0, stream>>>(Wo, wto, D_, D_, (size_t)D_*D_, (size_t)D_*D_, 0);
  transpose_cvt<<<dim3(16, 16, L_), tblk, 0, stream>>>(Win, wtin, D_, D_, (size_t)D_*D_, (size_t)D_*D_, 0);
  transpose_cvt<<<dim3(16, 16, L_), tblk, 0, stream>>>(Wgate, wtgate, D_, D_, (size_t)D_*D_, (size_t)D_*D_, 0);
  transpose_cvt<<<dim3(16, 32, L_), tblk, 0, stream>>>(Wedge, wtedge, 2*D_, D_, (size_t)2*D_*D_, (size_t)2*D_*D_, 0);
  transpose_cvt<<<dim3(V_/32, 16, 1), tblk, 0, stream>>>(Whead, wthead, D_, V_, (size_t)D_*V_, (size_t)D_*V_, 0);
  pack_qkv_bias<<<(L_ * 3 * D_) / 256, 256, 0, stream>>>(bq, bk, bv, bqkv);

  embed_k<<<M_, 256, 0, stream>>>(ids, tok, pos, hbuf);

  dim3 g64(M_ / 64, D_ / 64);         // (64,8) -> 512 blocks
  dim3 gqkv(M_ / 64, 3 * D_ / 128);   // (64,12) -> 768 blocks
  for (int l = 0; l < L_; ++l) {
    size_t wofs = (size_t)l * D_ * D_;
    ln4_k<<<M_ / 4, 256, 0, stream>>>(hbuf, ln1w + l * D_, ln1b + l * D_, xb);
    gemm3_k<0,4,128><<<gqkv, 256, 0, stream>>>(xb, wqkv + (size_t)l * 3 * D_ * D_,
        bqkv + (size_t)l * 3 * D_, nullptr, qkvb, nullptr, nullptr, zpad, M_, 3 * D_, D_);
    fattn_k<<<B_ * H_ * (S_ / 64), 256, 0, stream>>>(qkvb, avb);
    gemm3_k<0,1,64><<<g64, 256, 0, stream>>>(avb, wto + wofs, bo + l * D_,
        hbuf, nullptr, nullptr, nullptr, zpad, M_, D_, D_);
    ln4_k<<<M_ / 4, 256, 0, stream>>>(hbuf, ln2w + l * D_, ln2b + l * D_, xb);
    gemm3_k<0,0,64><<<g64, 256, 0, stream>>>(xb, wtin + wofs, bin + l * D_,
        tbuf, tbf, nullptr, nullptr, zpad, M_, D_, D_);
    // TreeFFN iter 0
    gemm3_k<1,2,64><<<g64, 256, 0, stream>>>(tbf, wtedge + (size_t)l * 2 * D_ * D_,
        bedge + l * D_, nullptr, msgb, nullptr, nullptr, zpad, M_, D_, 2 * D_);
    gemm3_k<2,3,64><<<g64, 256, 0, stream>>>(msgb, wtgate + wofs, bgate + l * D_,
        tbuf, tbf, msgb, nullptr, zpad, M_, D_, D_);
    // TreeFFN iter 1 + fused residual h += t
    gemm3_k<1,2,64><<<g64, 256, 0, stream>>>(tbf, wtedge + (size_t)l * 2 * D_ * D_,
        bedge + l * D_, nullptr, msgb, nullptr, nullptr, zpad, M_, D_, 2 * D_);
    gemm3_k<2,5,64><<<g64, 256, 0, stream>>>(msgb, wtgate + wofs, bgate + l * D_,
        tbuf, nullptr, msgb, hbuf, zpad, M_, D_, D_);
  }
  ln4_k<<<M_ / 4, 256, 0, stream>>>(hbuf, lnfw, lnfb, xb);
  gemm2_k<<<dim3(M_ / 128, V_ / 128), 256, 0, stream>>>(xb, wthead, out, M_, V_, D_);
}

// Round 7
// 1005.217 us; speedup vs baseline: 6.3861x; 1.0698x over previous
//
#include <hip/hip_runtime.h>
#include <hip/hip_bf16.h>
#include <stdint.h>

#define V_ 32000
#define D_ 512
#define H_ 8
#define L_ 6
#define S_ 1024
#define B_ 4
#define DH_ 64
#define M_ (B_*S_)   // 4096

typedef __attribute__((ext_vector_type(8))) short bf16x8;
typedef __attribute__((ext_vector_type(4))) short short4b;
typedef __attribute__((ext_vector_type(4))) float f32x4;

__device__ __forceinline__ short f2bs(float f) {
  union { float f; uint32_t u; } x; x.f = f;
  uint32_t r = (x.u + 0x7FFFu + ((x.u >> 16) & 1u)) >> 16;
  return (short)r;
}
__device__ __forceinline__ float bs2f(short s) {
  union { uint32_t u; float f; } x; x.u = ((uint32_t)(uint16_t)s) << 16;
  return x.f;
}

__device__ __forceinline__ f32x4 mfma16(bf16x8 a, bf16x8 b, f32x4 c) {
  return __builtin_amdgcn_mfma_f32_16x16x32_bf16(a, b, c, 0, 0, 0);
}

// async global->LDS, 16B per lane; LDS dest = wave-uniform base + lane*16
__device__ __forceinline__ void gload16(const short* g, char* lds) {
  __builtin_amdgcn_global_load_lds(
      (const __attribute__((address_space(1))) uint32_t*)g,
      (__attribute__((address_space(3))) uint32_t*)lds, 16, 0, 0);
}

template<int N> __device__ __forceinline__ void waitvm() {
  if constexpr (N == 0) asm volatile("s_waitcnt vmcnt(0)" ::: "memory");
  else if constexpr (N == 4) asm volatile("s_waitcnt vmcnt(4)" ::: "memory");
  else if constexpr (N == 6) asm volatile("s_waitcnt vmcnt(6)" ::: "memory");
  else if constexpr (N == 8) asm volatile("s_waitcnt vmcnt(8)" ::: "memory");
}

// ---- transpose + fp32->bf16 convert: out[(orow0+n)*K + k] = in[k*N+n] ----
__global__ __launch_bounds__(256) void transpose_cvt(const float* __restrict__ in,
    short* __restrict__ out, int K, int N, size_t in_slab, size_t out_slab, int orow0) {
  __shared__ float tile[32][33];
  const float* inp = in + (size_t)blockIdx.z * in_slab;
  short* outp = out + (size_t)blockIdx.z * out_slab;
  int kb = blockIdx.y * 32, nb = blockIdx.x * 32;
  int tx = threadIdx.x, ty = threadIdx.y;   // block (32,8)
  for (int r = ty; r < 32; r += 8) {
    int k = kb + r, n = nb + tx;
    tile[r][tx] = (k < K && n < N) ? inp[(size_t)k * N + n] : 0.f;
  }
  __syncthreads();
  for (int r = ty; r < 32; r += 8) {
    int n = nb + r, k = kb + tx;
    if (n < N && k < K) outp[(size_t)(orow0 + n) * K + k] = f2bs(tile[tx][r]);
  }
}

__global__ __launch_bounds__(256) void pack_qkv_bias(const float* __restrict__ bq,
    const float* __restrict__ bk, const float* __restrict__ bv, float* __restrict__ o) {
  int i = blockIdx.x * 256 + threadIdx.x;   // < L_*1536
  int l = i / 1536, c = i - l * 1536;
  float v = (c < 512) ? bq[l * 512 + c] : (c < 1024) ? bk[l * 512 + c - 512]
                                                     : bv[l * 512 + c - 1024];
  o[i] = v;
}

// ---- embedding ----
__global__ __launch_bounds__(256) void embed_k(const int* __restrict__ ids,
    const float* __restrict__ tok, const float* __restrict__ pos, float* __restrict__ h) {
  int bs = blockIdx.x;
  int tid = threadIdx.x;
  int s = bs & (S_ - 1);
  int id = ids[bs];
  float2 te = *(const float2*)(tok + (size_t)id * D_ + tid * 2);
  float2 pe = *(const float2*)(pos + (size_t)s * D_ + tid * 2);
  float2 r; r.x = te.x + pe.x; r.y = te.y + pe.y;
  *(float2*)(h + (size_t)bs * D_ + tid * 2) = r;
}

// ---- LayerNorm, one wave per row, 4 rows/block, no LDS ----
__global__ __launch_bounds__(256) void ln4_k(const float* __restrict__ in,
    const float* __restrict__ w, const float* __restrict__ bb, short* __restrict__ outb) {
  int wv = threadIdx.x >> 6, lane = threadIdx.x & 63;
  int row = blockIdx.x * 4 + wv;
  const float* x = in + (size_t)row * D_ + lane * 8;
  float4 v0 = *(const float4*)x;
  float4 v1 = *(const float4*)(x + 4);
  float s = v0.x + v0.y + v0.z + v0.w + v1.x + v1.y + v1.z + v1.w;
  #pragma unroll
  for (int o = 32; o; o >>= 1) s += __shfl_xor(s, o);
  float mu = s * (1.f / D_);
  float d[8] = {v0.x-mu, v0.y-mu, v0.z-mu, v0.w-mu, v1.x-mu, v1.y-mu, v1.z-mu, v1.w-mu};
  float s2 = 0.f;
  #pragma unroll
  for (int j = 0; j < 8; ++j) s2 += d[j] * d[j];
  #pragma unroll
  for (int o = 32; o; o >>= 1) s2 += __shfl_xor(s2, o);
  float rs = rsqrtf(s2 * (1.f / D_) + 1e-5f);
  float4 w0 = *(const float4*)(w + lane * 8);
  float4 w1 = *(const float4*)(w + lane * 8 + 4);
  float4 b0 = *(const float4*)(bb + lane * 8);
  float4 b1 = *(const float4*)(bb + lane * 8 + 4);
  float wj[8] = {w0.x,w0.y,w0.z,w0.w,w1.x,w1.y,w1.z,w1.w};
  float bj[8] = {b0.x,b0.y,b0.z,b0.w,b1.x,b1.y,b1.z,b1.w};
  short o8[8];
  #pragma unroll
  for (int j = 0; j < 8; ++j) o8[j] = f2bs(d[j] * rs * wj[j] + bj[j]);
  *(uint4*)(outb + (size_t)row * D_ + lane * 8) = *(uint4*)o8;
}

// ========== 64xBN MFMA GEMM, BK=64, dbuf + counted vmcnt ==========
template<int AMODE, int EMODE, int BN>
__global__ __launch_bounds__(256) void gemm3_k(
    const short* __restrict__ A, const short* __restrict__ Wt,
    const float* __restrict__ bias, float* __restrict__ Cf,
    short* __restrict__ Cb, const short* __restrict__ Agg,
    float* __restrict__ Hf, const short* __restrict__ zpad,
    int M, int N, int K)
{
  constexpr int NF = BN / 32;             // B frags per wave
  constexpr int BR = BN / 32;             // B staging rounds (32 rows each)
  constexpr int LOADS = 2 + BR;           // gload_lds per wave per stage
  __shared__ __align__(16) char As[2][64 * 128];
  __shared__ __align__(16) char Bs[2][BN * 128];
  const int tid = threadIdx.x;
  const int lane = tid & 63, w = tid >> 6;
  const int m0 = blockIdx.x * 64, n0 = blockIdx.y * BN;
  const int l15 = lane & 15, l4 = lane >> 4;
  const int wm = (w >> 1) * 32, wn = (w & 1) * (BN / 2);

  const int lrow_b = tid >> 3;            // 0..31
  const int kel0 = (tid & 7) * 8;
  const short* agp[2];
  const short* agpHi[2];
  #pragma unroll
  for (int r = 0; r < 2; ++r) {
    int lrow = r * 32 + lrow_b;
    int row = m0 + lrow;
    int kel = kel0 ^ ((lrow & 7) << 3);
    if (AMODE == 0) {
      agp[r] = A + (size_t)row * K + kel;
    } else if (AMODE == 1) {
      agp[r]   = A + (size_t)row * D_ + kel;
      agpHi[r] = ((row & (S_ - 1)) == (S_ - 1)) ? zpad + kel
                                                : A + (size_t)(row + 1) * D_ + kel;
    } else {
      agp[r] = ((row & (S_ - 1)) == 0) ? zpad + kel : A + (size_t)(row - 1) * D_ + kel;
    }
  }
  const short* bgp[BR];
  #pragma unroll
  for (int r = 0; r < BR; ++r) {
    int lrow = r * 32 + lrow_b;
    int kel = kel0 ^ ((lrow & 7) << 3);
    bgp[r] = Wt + (size_t)(n0 + lrow) * K + kel;
  }

  auto stage = [&](int buf, int k0) {
    #pragma unroll
    for (int r = 0; r < 2; ++r) {
      const short* gp;
      if (AMODE == 1) gp = (k0 < D_) ? agp[r] + k0 : agpHi[r] + (k0 - D_);
      else gp = agp[r] + k0;
      gload16(gp, As[buf] + r * 4096 + w * 1024);
    }
    #pragma unroll
    for (int r = 0; r < BR; ++r)
      gload16(bgp[r] + k0, Bs[buf] + r * 4096 + w * 1024);
  };

  const int rswz = (l15 & 7) << 4;
  int aoff[2], boff[NF];
  #pragma unroll
  for (int i = 0; i < 2; ++i) aoff[i] = (wm + i * 16 + l15) * 128;
  #pragma unroll
  for (int j = 0; j < NF; ++j) boff[j] = (wn + j * 16 + l15) * 128;

  f32x4 acc[2][NF] = {};

  const int nk = K >> 6;
  stage(0, 0);
  for (int t = 0; t < nk; ++t) {
    const int cur = t & 1;
    if (t + 1 < nk) { stage(cur ^ 1, (t + 1) * 64); waitvm<LOADS>(); }
    else waitvm<0>();
    __syncthreads();
    #pragma unroll
    for (int kk = 0; kk < 2; ++kk) {
      const int cb = (kk * 64 + l4 * 16) ^ rswz;
      bf16x8 af[2], bfr[NF];
      #pragma unroll
      for (int i = 0; i < 2; ++i) af[i] = *(const bf16x8*)(As[cur] + aoff[i] + cb);
      #pragma unroll
      for (int j = 0; j < NF; ++j) bfr[j] = *(const bf16x8*)(Bs[cur] + boff[j] + cb);
      __builtin_amdgcn_s_setprio(1);
      #pragma unroll
      for (int i = 0; i < 2; ++i)
        #pragma unroll
        for (int j = 0; j < NF; ++j)
          acc[i][j] = mfma16(af[i], bfr[j], acc[i][j]);
      __builtin_amdgcn_s_setprio(0);
    }
    __syncthreads();
  }

  const int rowb = m0 + wm + l4 * 4;
  const int colb = n0 + wn + l15;
  #pragma unroll
  for (int i = 0; i < 2; ++i) {
    #pragma unroll
    for (int j = 0; j < NF; ++j) {
      int col = colb + j * 16;
      float bias_v = bias ? bias[col] : 0.f;
      #pragma unroll
      for (int r = 0; r < 4; ++r) {
        int row = rowb + i * 16 + r;
        size_t idx = (size_t)row * N + col;
        float v = acc[i][j][r] + bias_v;
        if (EMODE == 0) {
          if (Cb) { Cf[idx] = v; Cb[idx] = f2bs(v); }
          else __builtin_nontemporal_store(v, &Cf[idx]);
        } else if (EMODE == 1) {
          Cf[idx] += v;
        } else if (EMODE == 2) {
          Cb[idx] = f2bs(fmaxf(v, 0.f));
        } else if (EMODE == 3) {
          float g = 1.f / (1.f + __expf(-v));
          float aggv = ((row & (S_ - 1)) == 0) ? 0.f : bs2f(Agg[idx - N]);
          float tn = Cf[idx] + g * aggv;
          Cf[idx] = tn; Cb[idx] = f2bs(tn);
        } else if (EMODE == 5) {
          float g = 1.f / (1.f + __expf(-v));
          float aggv = ((row & (S_ - 1)) == 0) ? 0.f : bs2f(Agg[idx - N]);
          Hf[idx] += Cf[idx] + g * aggv;
        } else {   // 4: QKV packed bf16; q cols scaled into exp2 domain
          float sc = (col < D_) ? 0.180336880f : 1.f;   // 0.125 * log2(e)
          Cb[idx] = f2bs(v * sc);
        }
      }
    }
  }
}

// ========== 128x128 MFMA GEMM (head), XCD-swizzled, dbuf + counted vmcnt ==========
__global__ __launch_bounds__(256) void gemm2_k(
    const short* __restrict__ A, const short* __restrict__ Wt,
    float* __restrict__ Cf, int M, int N, int K)
{
  __shared__ __align__(16) char As[2][128 * 128];
  __shared__ __align__(16) char Bs[2][128 * 128];
  const int tid = threadIdx.x;
  const int lane = tid & 63, w = tid >> 6;
  // XCD-bijective swizzle (nwg % 8 == 0): each XCD gets a contiguous chunk,
  // m-fastest within the chunk -> B col-panel resident in that XCD's L2.
  const int nwg = gridDim.x * gridDim.y;
  const int bid = blockIdx.x + blockIdx.y * gridDim.x;
  const int swz = (bid & 7) * (nwg >> 3) + (bid >> 3);
  const int m0 = (swz % gridDim.x) * 128, n0 = (swz / gridDim.x) * 128;
  const int l15 = lane & 15, l4 = lane >> 4;
  const int wm = (w >> 1) * 64, wn = (w & 1) * 64;

  const int lrow_b = tid >> 3;
  const int kel0 = (tid & 7) * 8;
  const short* agp[4];
  const short* bgp[4];
  #pragma unroll
  for (int r = 0; r < 4; ++r) {
    int lrow = r * 32 + lrow_b;
    int kel = kel0 ^ ((lrow & 7) << 3);
    agp[r] = A + (size_t)(m0 + lrow) * K + kel;
    bgp[r] = Wt + (size_t)(n0 + lrow) * K + kel;
  }
  auto stage = [&](int buf, int k0) {
    #pragma unroll
    for (int r = 0; r < 4; ++r) gload16(agp[r] + k0, As[buf] + r * 4096 + w * 1024);
    #pragma unroll
    for (int r = 0; r < 4; ++r) gload16(bgp[r] + k0, Bs[buf] + r * 4096 + w * 1024);
  };

  const int rswz = (l15 & 7) << 4;
  int aoff[4], boff[4];
  #pragma unroll
  for (int i = 0; i < 4; ++i) aoff[i] = (wm + i * 16 + l15) * 128;
  #pragma unroll
  for (int j = 0; j < 4; ++j) boff[j] = (wn + j * 16 + l15) * 128;

  f32x4 acc[4][4] = {};
  const int nk = K >> 6;
  stage(0, 0);
  for (int t = 0; t < nk; ++t) {
    const int cur = t & 1;
    if (t + 1 < nk) { stage(cur ^ 1, (t + 1) * 64); waitvm<8>(); }
    else waitvm<0>();
    __syncthreads();
    #pragma unroll
    for (int kk = 0; kk < 2; ++kk) {
      const int cb = (kk * 64 + l4 * 16) ^ rswz;
      bf16x8 af[4], bfr[4];
      #pragma unroll
      for (int i = 0; i < 4; ++i) af[i] = *(const bf16x8*)(As[cur] + aoff[i] + cb);
      #pragma unroll
      for (int j = 0; j < 4; ++j) bfr[j] = *(const bf16x8*)(Bs[cur] + boff[j] + cb);
      __builtin_amdgcn_s_setprio(1);
      #pragma unroll
      for (int i = 0; i < 4; ++i)
        #pragma unroll
        for (int j = 0; j < 4; ++j)
          acc[i][j] = mfma16(af[i], bfr[j], acc[i][j]);
      __builtin_amdgcn_s_setprio(0);
    }
    __syncthreads();
  }

  const int rowb = m0 + wm + l4 * 4;
  const int colb = n0 + wn + l15;
  #pragma unroll
  for (int i = 0; i < 4; ++i)
    #pragma unroll
    for (int j = 0; j < 4; ++j)
      #pragma unroll
      for (int r = 0; r < 4; ++r) {
        size_t idx = (size_t)(rowb + i * 16 + r) * N + colb + j * 16;
        __builtin_nontemporal_store(acc[i][j][r], &Cf[idx]);
      }
}

// ---- flash attention, swapped QK^T: S^T = mfma(K,Q) so softmax is lane-local.
//      P^T goes through a small per-wave LDS buffer (packed b64 writes, b128 reads);
//      PV = O^T = mfma(V^T, P^T) with the verified Vt[64][72] XOR-swizzled layout. ----
// Qkv packed [M][3*D_] bf16, Q pre-scaled by 0.125*log2(e) (exp2 domain).
__global__ __launch_bounds__(256) void fattn_k(const short* __restrict__ Qkv,
    short* __restrict__ avb)
{
  __shared__ short Ks[64][72];        // [key][dh]
  __shared__ short Vt[64][72];        // [dh][key ^ swz]
  __shared__ short Pt[4][16][72];     // per-wave P^T as [q][key]
  const int QS = 3 * D_;
  const int tid = threadIdx.x, lane = tid & 63, w = tid >> 6;
  const int bx = blockIdx.x;
  const int qt = 15 - (bx >> 5);      // heavy tiles first
  const int bh = bx & 31, b = bh >> 3, hh = bh & 7;
  const int l15 = lane & 15, g = lane >> 4;

  const int qrow = qt * 64 + w * 16 + l15;   // this lane's q (output column)
  const short* qptr = Qkv + (size_t)(b * S_ + qrow) * QS + hh * DH_;
  bf16x8 qa0 = *(const bf16x8*)(qptr + g * 8);
  bf16x8 qa1 = *(const bf16x8*)(qptr + 32 + g * 8);

  f32x4 o[4] = {};        // o[nt][r] = O[qrow][d = nt*16 + g*4 + r]
  float mx = -1e30f, lsum = 0.f;

  auto gptr = [&](int kt, int i) {
    int c = tid + i * 256;
    int key = c >> 3, d0 = (c & 7) * 8;
    return Qkv + (size_t)(b * S_ + kt * 64 + key) * QS + hh * DH_ + d0;
  };
  uint4 kvA[2], vvA[2], kvB[2], vvB[2];
  auto load_t = [&](int kt, uint4 kv[2], uint4 vv[2]) {
    #pragma unroll
    for (int i = 0; i < 2; ++i) {
      const short* base = gptr(kt, i);
      kv[i] = *(const uint4*)(base + D_);
      vv[i] = *(const uint4*)(base + 2 * D_);
    }
  };
  auto store_t = [&](uint4 kv[2], uint4 vv[2]) {
    #pragma unroll
    for (int i = 0; i < 2; ++i) {
      int c = tid + i * 256;
      int key = c >> 3, d0 = (c & 7) * 8;
      *(uint4*)&Ks[key][d0] = kv[i];
      short vs[8]; *(uint4*)vs = vv[i];
      int a = (c & 7);
      #pragma unroll
      for (int j = 0; j < 8; ++j)
        Vt[d0 + j][key ^ (a << 3)] = vs[j];
    }
  };

  auto compute = [&](int kt) {
    const int key0 = kt * 64;
    // S^T = K Q^T : A = K (rows f*16+g*4+r = keys), B = Q^T (col l15 = q)
    f32x4 sc[4] = {};
    __builtin_amdgcn_s_setprio(1);
    #pragma unroll
    for (int f = 0; f < 4; ++f) {
      bf16x8 ka0 = *(const bf16x8*)&Ks[f * 16 + l15][g * 8];
      bf16x8 ka1 = *(const bf16x8*)&Ks[f * 16 + l15][32 + g * 8];
      sc[f] = mfma16(ka0, qa0, sc[f]);
      sc[f] = mfma16(ka1, qa1, sc[f]);
    }
    __builtin_amdgcn_s_setprio(0);

    // softmax: sc[f][r] = S[qrow][key0 + f*16 + g*4 + r]; q is lane-local.
    float s[16];
    #pragma unroll
    for (int f = 0; f < 4; ++f)
      #pragma unroll
      for (int r = 0; r < 4; ++r)
        s[f * 4 + r] = sc[f][r];
    if (kt == qt) {
      #pragma unroll
      for (int f = 0; f < 4; ++f)
        #pragma unroll
        for (int r = 0; r < 4; ++r)
          if (key0 + f * 16 + g * 4 + r > qrow) s[f * 4 + r] = -1e30f;
    }
    float cm = s[0];
    #pragma unroll
    for (int i = 1; i < 16; ++i) cm = fmaxf(cm, s[i]);
    cm = fmaxf(cm, __shfl_xor(cm, 16));
    cm = fmaxf(cm, __shfl_xor(cm, 32));
    float mn = fmaxf(mx, cm);
    float fr = exp2f(mx - mn);
    mx = mn;
    float p[16], ss = 0.f;
    #pragma unroll
    for (int i = 0; i < 16; ++i) { p[i] = exp2f(s[i] - mn); ss += p[i]; }
    ss += __shfl_xor(ss, 16);
    ss += __shfl_xor(ss, 32);
    lsum = lsum * fr + ss;
    #pragma unroll
    for (int nt = 0; nt < 4; ++nt)
      #pragma unroll
      for (int r = 0; r < 4; ++r) o[nt][r] *= fr;

    // P^T -> per-wave LDS, packed: lane's r-values are 4 consecutive keys.
    #pragma unroll
    for (int f = 0; f < 4; ++f) {
      short tmp[4];
      #pragma unroll
      for (int r = 0; r < 4; ++r) tmp[r] = f2bs(p[f * 4 + r]);
      *(uint2*)&Pt[w][l15][f * 16 + g * 4] = *(uint2*)tmp;
    }
    __builtin_amdgcn_sched_barrier(0);   // keep writes before reads (same wave)
    bf16x8 pb0 = *(const bf16x8*)&Pt[w][l15][g * 8];        // keys g*8..+7
    bf16x8 pb1 = *(const bf16x8*)&Pt[w][l15][32 + g * 8];   // keys 32+g*8..+7

    // O^T += V^T P^T : A = V^T (rows d = nt*16+l15, k = keys), B = P^T
    __builtin_amdgcn_s_setprio(1);
    #pragma unroll
    for (int nt = 0; nt < 4; ++nt) {
      int dim = nt * 16 + l15;
      int vswz = ((dim >> 3) & 7) << 3;
      bf16x8 va0 = *(const bf16x8*)&Vt[dim][(g * 8) ^ vswz];
      bf16x8 va1 = *(const bf16x8*)&Vt[dim][(32 + g * 8) ^ vswz];
      o[nt] = mfma16(va0, pb0, o[nt]);
      o[nt] = mfma16(va1, pb1, o[nt]);
    }
    __builtin_amdgcn_s_setprio(0);
  };

  const int ntiles = qt + 1;
  load_t(0, kvA, vvA);
  int kt = 0;
  while (true) {
    __syncthreads();
    store_t(kvA, vvA);
    if (kt + 1 < ntiles) load_t(kt + 1, kvB, vvB);
    __syncthreads();
    compute(kt);
    ++kt; if (kt >= ntiles) break;
    __syncthreads();
    store_t(kvB, vvB);
    if (kt + 1 < ntiles) load_t(kt + 1, kvA, vvA);
    __syncthreads();
    compute(kt);
    ++kt; if (kt >= ntiles) break;
  }

  const float inv = 1.f / lsum;
  #pragma unroll
  for (int nt = 0; nt < 4; ++nt) {
    short ov[4];
    #pragma unroll
    for (int r = 0; r < 4; ++r) ov[r] = f2bs(o[nt][r] * inv);
    *(short4b*)(avb + (size_t)(b * S_ + qrow) * D_ + hh * DH_ + nt * 16 + g * 4) =
        *(short4b*)ov;
  }
}

extern "C" void kernel_launch(void* const* d_in, const int* in_sizes, int n_in,
                              void* d_out, int out_size, void* d_ws, size_t ws_size,
                              hipStream_t stream) {
  const int*   ids   = (const int*)d_in[0];
  const float* tok   = (const float*)d_in[1];
  const float* pos   = (const float*)d_in[2];
  const float* Wq    = (const float*)d_in[3];
  const float* bq    = (const float*)d_in[4];
  const float* Wk    = (const float*)d_in[5];
  const float* bk    = (const float*)d_in[6];
  const float* Wv    = (const float*)d_in[7];
  const float* bv    = (const float*)d_in[8];
  const float* Wo    = (const float*)d_in[9];
  const float* bo    = (const float*)d_in[10];
  const float* ln1w  = (const float*)d_in[11];
  const float* ln1b  = (const float*)d_in[12];
  const float* ln2w  = (const float*)d_in[13];
  const float* ln2b  = (const float*)d_in[14];
  const float* Win   = (const float*)d_in[15];
  const float* bin   = (const float*)d_in[16];
  const float* Wedge = (const float*)d_in[17];
  const float* bedge = (const float*)d_in[18];
  const float* Wgate = (const float*)d_in[19];
  const float* bgate = (const float*)d_in[20];
  const float* lnfw  = (const float*)d_in[21];
  const float* lnfb  = (const float*)d_in[22];
  const float* Whead = (const float*)d_in[23];
  float* out = (float*)d_out;

  char* ws = (char*)d_ws;
  size_t off = 0;
  auto alloc = [&](size_t bytes) {
    void* p = ws + off;
    off = (off + bytes + 255) & ~(size_t)255;
    return p;
  };
  short* wqkv   = (short*)alloc((size_t)L_ * 3 * D_ * D_ * 2);
  float* bqkv   = (float*)alloc((size_t)L_ * 3 * D_ * 4);
  short* wto    = (short*)alloc((size_t)L_ * D_ * D_ * 2);
  short* wtin   = (short*)alloc((size_t)L_ * D_ * D_ * 2);
  short* wtgate = (short*)alloc((size_t)L_ * D_ * D_ * 2);
  short* wtedge = (short*)alloc((size_t)L_ * 2 * D_ * D_ * 2);
  short* wthead = (short*)alloc((size_t)V_ * D_ * 2);
  short* zpad   = (short*)alloc(4096);
  float* hbuf   = (float*)alloc((size_t)M_ * D_ * 4);
  short* xb     = (short*)alloc((size_t)M_ * D_ * 2);
  short* qkvb   = (short*)alloc((size_t)M_ * 3 * D_ * 2);
  short* avb    = (short*)alloc((size_t)M_ * D_ * 2);
  float* tbuf   = (float*)alloc((size_t)M_ * D_ * 4);
  short* tbf    = (short*)alloc((size_t)M_ * D_ * 2);
  short* msgb   = (short*)alloc((size_t)M_ * D_ * 2);
  (void)ws_size; (void)in_sizes; (void)n_in; (void)out_size;

  hipMemsetAsync(zpad, 0, 4096, stream);

  dim3 tblk(32, 8);
  transpose_cvt<<<dim3(16, 16, L_), tblk, 0, stream>>>(Wq, wqkv, D_, D_, (size_t)D_*D_, (size_t)3*D_*D_, 0);
  transpose_cvt<<<dim3(16, 16, L_), tblk, 0, stream>>>(Wk, wqkv, D_, D_, (size_t)D_*D_, (size_t)3*D_*D_, D_);
  transpose_cvt<<<dim3(16, 16, L_), tblk, 0, stream>>>(Wv, wqkv, D_, D_, (size_t)D_*D_, (size_t)3*D_*D_, 2*D_);
  transpose_cvt<<<dim3(16, 16, L_), tblk, 0, stream>>>(Wo, wto, D_, D_, (size_t)D_*D_, (size_t)D_*D_, 0);
  transpose_cvt<<<dim3(16, 16, L_), tblk, 0, stream>>>(Win, wtin, D_, D_, (size_t)D_*D_, (size_t)D_*D_, 0);
  transpose_cvt<<<dim3(16, 16, L_), tblk, 0, stream>>>(Wgate, wtgate, D_, D_, (size_t)D_*D_, (size_t)D_*D_, 0);
  transpose_cvt<<<dim3(16, 32, L_), tblk, 0, stream>>>(Wedge, wtedge, 2*D_, D_, (size_t)2*D_*D_, (size_t)2*D_*D_, 0);
  transpose_cvt<<<dim3(V_/32, 16, 1), tblk, 0, stream>>>(Whead, wthead, D_, V_, (size_t)D_*V_, (size_t)D_*V_, 0);
  pack_qkv_bias<<<(L_ * 3 * D_) / 256, 256, 0, stream>>>(bq, bk, bv, bqkv);

  embed_k<<<M_, 256, 0, stream>>>(ids, tok, pos, hbuf);

  dim3 g64(M_ / 64, D_ / 64);         // (64,8) -> 512 blocks
  dim3 gqkv(M_ / 64, 3 * D_ / 128);   // (64,12) -> 768 blocks
  for (int l = 0; l < L_; ++l) {
    size_t wofs = (size_t)l * D_ * D_;
    ln4_k<<<M_ / 4, 256, 0, stream>>>(hbuf, ln1w + l * D_, ln1b + l * D_, xb);
    gemm3_k<0,4,128><<<gqkv, 256, 0, stream>>>(xb, wqkv + (size_t)l * 3 * D_ * D_,
        bqkv + (size_t)l * 3 * D_, nullptr, qkvb, nullptr, nullptr, zpad, M_, 3 * D_, D_);
    fattn_k<<<B_ * H_ * (S_ / 64), 256, 0, stream>>>(qkvb, avb);
    gemm3_k<0,1,64><<<g64, 256, 0, stream>>>(avb, wto + wofs, bo + l * D_,
        hbuf, nullptr, nullptr, nullptr, zpad, M_, D_, D_);
    ln4_k<<<M_ / 4, 256, 0, stream>>>(hbuf, ln2w + l * D_, ln2b + l * D_, xb);
    gemm3_k<0,0,64><<<g64, 256, 0, stream>>>(xb, wtin + wofs, bin + l * D_,
        tbuf, tbf, nullptr, nullptr, zpad, M_, D_, D_);
    // TreeFFN iter 0
    gemm3_k<1,2,64><<<g64, 256, 0, stream>>>(tbf, wtedge + (size_t)l * 2 * D_ * D_,
        bedge + l * D_, nullptr, msgb, nullptr, nullptr, zpad, M_, D_, 2 * D_);
    gemm3_k<2,3,64><<<g64, 256, 0, stream>>>(msgb, wtgate + wofs, bgate + l * D_,
        tbuf, tbf, msgb, nullptr, zpad, M_, D_, D_);
    // TreeFFN iter 1 + fused residual h += t
    gemm3_k<1,2,64><<<g64, 256, 0, stream>>>(tbf, wtedge + (size_t)l * 2 * D_ * D_,
        bedge + l * D_, nullptr, msgb, nullptr, nullptr, zpad, M_, D_, 2 * D_);
    gemm3_k<2,5,64><<<g64, 256, 0, stream>>>(msgb, wtgate + wofs, bgate + l * D_,
        tbuf, nullptr, msgb, hbuf, zpad, M_, D_, D_);
  }
  ln4_k<<<M_ / 4, 256, 0, stream>>>(hbuf, lnfw, lnfb, xb);
  gemm2_k<<<dim3(M_ / 128, V_ / 128), 256, 0, stream>>>(xb, wthead, out, M_, V_, D_);
}